// Round 1
// baseline (1551.323 us; speedup 1.0000x reference)
//
#include <hip/hip_runtime.h>
#include <math.h>

// Problem constants (MultiHeadAttention: B=2, S=2048, D=512, H=8, HD=64)
constexpr int B_ = 2, S_ = 2048, D_ = 512, H_ = 8, HD_ = 64;
constexpr int M_ = B_ * S_;   // 4096 rows for the projection GEMMs

// ---------------------------------------------------------------------------
// GEMM: Y = X @ W^T + bias   (X:[M,512], W:[512,512] row-major, Y:[M,512])
// BM=128, BN=64, BK=16, 256 threads, 8x4 microtile. fp32, LDS staged.
// gridDim.z selects one of up to 3 (X,W,bias,Y) pointer sets (fused QKV).
// ---------------------------------------------------------------------------
constexpr int GBM = 128, GBN = 64, GBK = 16;

__global__ __launch_bounds__(256) void gemm_xwT3(
    const float* __restrict__ X0, const float* __restrict__ W0,
    const float* __restrict__ bi0, float* __restrict__ Y0,
    const float* __restrict__ X1, const float* __restrict__ W1,
    const float* __restrict__ bi1, float* __restrict__ Y1,
    const float* __restrict__ X2, const float* __restrict__ W2,
    const float* __restrict__ bi2, float* __restrict__ Y2)
{
  const float* X; const float* W; const float* bias; float* Y;
  if (blockIdx.z == 0)      { X = X0; W = W0; bias = bi0; Y = Y0; }
  else if (blockIdx.z == 1) { X = X1; W = W1; bias = bi1; Y = Y1; }
  else                      { X = X2; W = W2; bias = bi2; Y = Y2; }

  // K-major LDS tiles (transposed store) so inner loop reads contiguous float4.
  __shared__ float Xs[GBK][GBM + 4];   // stride 132 floats (528B, 16B-aligned)
  __shared__ float Ws[GBK][GBN + 4];   // stride 68 floats (272B, 16B-aligned)

  const int tid = threadIdx.x;
  const int tx = tid & 15;          // output cols tx*4 .. tx*4+3
  const int ty = tid >> 4;          // output rows ty*8 .. ty*8+7
  const int m0 = blockIdx.x * GBM;
  const int n0 = blockIdx.y * GBN;

  const int xr = tid >> 1, xc = (tid & 1) * 8;   // X tile load: 128x16
  const int wr = tid >> 2, wc = (tid & 3) * 4;   // W tile load: 64x16

  float acc[8][4] = {};

#pragma unroll 1
  for (int k0 = 0; k0 < D_; k0 += GBK) {
    float4 xa = *(const float4*)&X[(size_t)(m0 + xr) * D_ + k0 + xc];
    float4 xb = *(const float4*)&X[(size_t)(m0 + xr) * D_ + k0 + xc + 4];
    float4 wa = *(const float4*)&W[(size_t)(n0 + wr) * D_ + k0 + wc];
    __syncthreads();   // previous iteration's reads complete before overwrite
    Xs[xc + 0][xr] = xa.x; Xs[xc + 1][xr] = xa.y;
    Xs[xc + 2][xr] = xa.z; Xs[xc + 3][xr] = xa.w;
    Xs[xc + 4][xr] = xb.x; Xs[xc + 5][xr] = xb.y;
    Xs[xc + 6][xr] = xb.z; Xs[xc + 7][xr] = xb.w;
    Ws[wc + 0][wr] = wa.x; Ws[wc + 1][wr] = wa.y;
    Ws[wc + 2][wr] = wa.z; Ws[wc + 3][wr] = wa.w;
    __syncthreads();

#pragma unroll
    for (int kk = 0; kk < GBK; ++kk) {
      float4 a0 = *(const float4*)&Xs[kk][ty * 8];
      float4 a1 = *(const float4*)&Xs[kk][ty * 8 + 4];
      float4 bv = *(const float4*)&Ws[kk][tx * 4];
      float a[8] = {a0.x, a0.y, a0.z, a0.w, a1.x, a1.y, a1.z, a1.w};
      float bb[4] = {bv.x, bv.y, bv.z, bv.w};
#pragma unroll
      for (int i = 0; i < 8; ++i)
#pragma unroll
        for (int j = 0; j < 4; ++j)
          acc[i][j] = fmaf(a[i], bb[j], acc[i][j]);
    }
  }

  float4 bias4 = *(const float4*)&bias[n0 + tx * 4];
#pragma unroll
  for (int i = 0; i < 8; ++i) {
    float4 o;
    o.x = acc[i][0] + bias4.x; o.y = acc[i][1] + bias4.y;
    o.z = acc[i][2] + bias4.z; o.w = acc[i][3] + bias4.w;
    *(float4*)&Y[(size_t)(m0 + ty * 8 + i) * D_ + n0 + tx * 4] = o;
  }
}

// ---------------------------------------------------------------------------
// Flash-style attention, fp32. Block: 64 q-rows of one (b,h); 4 waves,
// each wave owns 16 q-rows. K-tile transposed in LDS (conflict-free column
// reads -> per-lane K-row fragment in registers); V row-major (per-lane
// V-column fragment). Online softmax with shfl-xor reductions.
// ---------------------------------------------------------------------------
__global__ __launch_bounds__(256) void attn_kernel(
    const float* __restrict__ qp, const float* __restrict__ kp,
    const float* __restrict__ vp, const int* __restrict__ mask,
    float* __restrict__ op)
{
  const int b = blockIdx.z, h = blockIdx.y;
  const int q0 = blockIdx.x * 64;
  const int tid = threadIdx.x;
  const int lane = tid & 63;
  const int w = tid >> 6;                 // wave 0..3 -> q-rows w*16..w*16+15

  __shared__ float Qs[64][HD_ + 4];       // [row][d], stride 68
  __shared__ float Kt[HD_][64 + 1];       // [d][j],   stride 65 (transposed)
  __shared__ float Vs[64][HD_ + 4];       // [j][d],   stride 68
  __shared__ float Ps[4][64];             // per-wave softmax-p row

  // ---- stage Q tile (once) ----
  {
    const int r = tid >> 2, c = (tid & 3) * 16;
    const float4* src =
        (const float4*)&qp[((size_t)b * S_ + q0 + r) * D_ + h * HD_ + c];
    float4* dst = (float4*)&Qs[r][c];
    dst[0] = src[0]; dst[1] = src[1]; dst[2] = src[2]; dst[3] = src[3];
  }

  float m_r[16], l_r[16], o_r[16];
#pragma unroll
  for (int r = 0; r < 16; ++r) { m_r[r] = -3.0e38f; l_r[r] = 0.f; o_r[r] = 0.f; }

  const int qrow_base = q0 + w * 16;
  const size_t mask_base = ((size_t)b * S_ + qrow_base) * S_;

#pragma unroll 1
  for (int kt = 0; kt < S_; kt += 64) {
    // prefetch this tile's mask (16 rows x 64 keys, coalesced per row)
    int mk[16];
#pragma unroll
    for (int r = 0; r < 16; ++r)
      mk[r] = mask[mask_base + (size_t)r * S_ + kt + lane];

    __syncthreads();
    {
      const int r = tid >> 2, c = (tid & 3) * 16;
      const float4* ks =
          (const float4*)&kp[((size_t)b * S_ + kt + r) * D_ + h * HD_ + c];
      const float4* vs =
          (const float4*)&vp[((size_t)b * S_ + kt + r) * D_ + h * HD_ + c];
#pragma unroll
      for (int g = 0; g < 4; ++g) {
        float4 kv = ks[g];
        Kt[c + g * 4 + 0][r] = kv.x; Kt[c + g * 4 + 1][r] = kv.y;
        Kt[c + g * 4 + 2][r] = kv.z; Kt[c + g * 4 + 3][r] = kv.w;
      }
      float4* vdst = (float4*)&Vs[r][c];
#pragma unroll
      for (int g = 0; g < 4; ++g) vdst[g] = vs[g];
    }
    __syncthreads();

    // K fragment: lane j holds key row j (column read of Kt, 2-way = free)
    float kreg[HD_];
#pragma unroll
    for (int d = 0; d < HD_; ++d) kreg[d] = Kt[d][lane];

    // QK^T: 16 rows, Q read as float4 broadcasts
    float sr[16];
#pragma unroll
    for (int r = 0; r < 16; ++r) {
      float s = 0.f;
#pragma unroll
      for (int g = 0; g < 16; ++g) {
        float4 qv = *(const float4*)&Qs[w * 16 + r][g * 4];
        s = fmaf(qv.x, kreg[4 * g + 0], s);
        s = fmaf(qv.y, kreg[4 * g + 1], s);
        s = fmaf(qv.z, kreg[4 * g + 2], s);
        s = fmaf(qv.w, kreg[4 * g + 3], s);
      }
      sr[r] = s;
    }

    // V fragment: lane d holds V column d (2-way = free)
    float vreg[64];
#pragma unroll
    for (int j = 0; j < 64; ++j) vreg[j] = Vs[j][lane];

#pragma unroll
    for (int r = 0; r < 16; ++r) {
      float logit = (mk[r] != 0) ? sr[r] * 0.125f : -1.0e9f;
      // row max across 64 lanes
      float mx = logit;
#pragma unroll
      for (int off = 32; off > 0; off >>= 1)
        mx = fmaxf(mx, __shfl_xor(mx, off, 64));
      float mnew = fmaxf(m_r[r], mx);
      float p = exp2f((logit - mnew) * 1.44269504f);
      float ps = p;
#pragma unroll
      for (int off = 32; off > 0; off >>= 1)
        ps += __shfl_xor(ps, off, 64);
      float corr = exp2f((m_r[r] - mnew) * 1.44269504f);
      m_r[r] = mnew;
      l_r[r] = l_r[r] * corr + ps;

      // distribute p to all lanes via per-wave LDS row (same-wave RAW: LDS
      // pipe is in-order per wave; compiler keeps order via alias analysis)
      Ps[w][lane] = p;
      float acc = 0.f;
#pragma unroll
      for (int g = 0; g < 16; ++g) {
        float4 pv = *(const float4*)&Ps[w][g * 4];
        acc = fmaf(pv.x, vreg[4 * g + 0], acc);
        acc = fmaf(pv.y, vreg[4 * g + 1], acc);
        acc = fmaf(pv.z, vreg[4 * g + 2], acc);
        acc = fmaf(pv.w, vreg[4 * g + 3], acc);
      }
      o_r[r] = o_r[r] * corr + acc;
    }
  }

  // epilogue: out[row][h*64 + lane] = o / l  (coalesced 256B per row)
#pragma unroll
  for (int r = 0; r < 16; ++r) {
    float inv = 1.0f / l_r[r];
    op[((size_t)b * S_ + q0 + w * 16 + r) * D_ + h * HD_ + lane] = o_r[r] * inv;
  }
}

// ---------------------------------------------------------------------------
extern "C" void kernel_launch(void* const* d_in, const int* in_sizes, int n_in,
                              void* d_out, int out_size, void* d_ws,
                              size_t ws_size, hipStream_t stream)
{
  const float* q_in = (const float*)d_in[0];
  const float* k_in = (const float*)d_in[1];
  const float* v_in = (const float*)d_in[2];
  const int*   mask = (const int*)d_in[3];
  const float* W1 = (const float*)d_in[4];
  const float* b1 = (const float*)d_in[5];
  const float* W2 = (const float*)d_in[6];
  const float* b2 = (const float*)d_in[7];
  const float* W3 = (const float*)d_in[8];
  const float* b3 = (const float*)d_in[9];
  const float* Wo = (const float*)d_in[10];
  const float* bo = (const float*)d_in[11];
  float* out = (float*)d_out;

  // workspace: q,k,v projections + attention output (4 x 8 MB fp32)
  float* qp = (float*)d_ws;
  float* kp = qp + (size_t)M_ * D_;
  float* vp = kp + (size_t)M_ * D_;
  float* op = vp + (size_t)M_ * D_;

  dim3 blk(256);
  // fused QKV projections: grid.z picks (X,W,b,Y)
  gemm_xwT3<<<dim3(M_ / GBM, D_ / GBN, 3), blk, 0, stream>>>(
      q_in, W1, b1, qp, k_in, W2, b2, kp, v_in, W3, b3, vp);
  // attention: 32 q-blocks x 8 heads x 2 batches = 512 blocks
  attn_kernel<<<dim3(S_ / 64, H_, B_), blk, 0, stream>>>(qp, kp, vp, mask, op);
  // output projection
  gemm_xwT3<<<dim3(M_ / GBM, D_ / GBN, 1), blk, 0, stream>>>(
      op, Wo, bo, out, op, Wo, bo, out, op, Wo, bo, out);
}

// Round 2
// 271.142 us; speedup vs baseline: 5.7214x; 5.7214x over previous
//
#include <hip/hip_runtime.h>
#include <math.h>

// MultiHeadAttention: B=2, S=2048, D=512, H=8, HD=64
constexpr int B_ = 2, S_ = 2048, D_ = 512, H_ = 8, HD_ = 64;
constexpr int M_ = B_ * S_;

typedef short s16x8 __attribute__((ext_vector_type(8)));    // 8 bf16 (A/B frag)
typedef float f32x4 __attribute__((ext_vector_type(4)));    // C/D frag
typedef unsigned short u16;
typedef unsigned short u16x8 __attribute__((ext_vector_type(8)));

static __device__ __forceinline__ u16 f32_to_bf16(float f) {
  union { float f; unsigned int u; } v; v.f = f;
  unsigned int u = v.u;
  unsigned int r = (u + 0x7FFFu + ((u >> 16) & 1u)) >> 16;   // RNE
  return (u16)r;
}

// ---------------------------------------------------------------------------
// GEMM: Y = X @ W^T + bias (X:[M,512] fp32, W:[512,512] fp32 row-major).
// MODE 0: fp32 out [M][D];  MODE 1: bf16 out [M][D];
// MODE 2: bf16 out transposed per head: vt[((b*H+h)*64+dd)][s]  (free V^T).
// BM=128, BN=64, BK=16, 256 thr, 8x4 microtile. ~fp32 vector roofline.
// ---------------------------------------------------------------------------
constexpr int GBM = 128, GBN = 64, GBK = 16;

template <int MODE>
__global__ __launch_bounds__(256) void gemm_xwT(
    const float* __restrict__ X, const float* __restrict__ W,
    const float* __restrict__ bias, void* __restrict__ Yv)
{
  __shared__ float Xs[GBK][GBM + 4];
  __shared__ float Ws[GBK][GBN + 4];

  const int tid = threadIdx.x;
  const int tx = tid & 15;
  const int ty = tid >> 4;
  const int m0 = blockIdx.x * GBM;
  const int n0 = blockIdx.y * GBN;

  const int xr = tid >> 1, xc = (tid & 1) * 8;
  const int wr = tid >> 2, wc = (tid & 3) * 4;

  float acc[8][4] = {};

#pragma unroll 1
  for (int k0 = 0; k0 < D_; k0 += GBK) {
    float4 xa = *(const float4*)&X[(size_t)(m0 + xr) * D_ + k0 + xc];
    float4 xb = *(const float4*)&X[(size_t)(m0 + xr) * D_ + k0 + xc + 4];
    float4 wa = *(const float4*)&W[(size_t)(n0 + wr) * D_ + k0 + wc];
    __syncthreads();
    Xs[xc + 0][xr] = xa.x; Xs[xc + 1][xr] = xa.y;
    Xs[xc + 2][xr] = xa.z; Xs[xc + 3][xr] = xa.w;
    Xs[xc + 4][xr] = xb.x; Xs[xc + 5][xr] = xb.y;
    Xs[xc + 6][xr] = xb.z; Xs[xc + 7][xr] = xb.w;
    Ws[wc + 0][wr] = wa.x; Ws[wc + 1][wr] = wa.y;
    Ws[wc + 2][wr] = wa.z; Ws[wc + 3][wr] = wa.w;
    __syncthreads();

#pragma unroll
    for (int kk = 0; kk < GBK; ++kk) {
      float4 a0 = *(const float4*)&Xs[kk][ty * 8];
      float4 a1 = *(const float4*)&Xs[kk][ty * 8 + 4];
      float4 bv = *(const float4*)&Ws[kk][tx * 4];
      float a[8] = {a0.x, a0.y, a0.z, a0.w, a1.x, a1.y, a1.z, a1.w};
      float bb[4] = {bv.x, bv.y, bv.z, bv.w};
#pragma unroll
      for (int i = 0; i < 8; ++i)
#pragma unroll
        for (int j = 0; j < 4; ++j)
          acc[i][j] = fmaf(a[i], bb[j], acc[i][j]);
    }
  }

  float4 bias4 = *(const float4*)&bias[n0 + tx * 4];
  float bb[4] = {bias4.x, bias4.y, bias4.z, bias4.w};

  if (MODE == 0) {
    float* Y = (float*)Yv;
#pragma unroll
    for (int i = 0; i < 8; ++i) {
      float4 o;
      o.x = acc[i][0] + bb[0]; o.y = acc[i][1] + bb[1];
      o.z = acc[i][2] + bb[2]; o.w = acc[i][3] + bb[3];
      *(float4*)&Y[(size_t)(m0 + ty * 8 + i) * D_ + n0 + tx * 4] = o;
    }
  } else if (MODE == 1) {
    u16* Y = (u16*)Yv;
#pragma unroll
    for (int i = 0; i < 8; ++i) {
      ushort4 o;
      o.x = f32_to_bf16(acc[i][0] + bb[0]);
      o.y = f32_to_bf16(acc[i][1] + bb[1]);
      o.z = f32_to_bf16(acc[i][2] + bb[2]);
      o.w = f32_to_bf16(acc[i][3] + bb[3]);
      *(ushort4*)&Y[(size_t)(m0 + ty * 8 + i) * D_ + n0 + tx * 4] = o;
    }
  } else {
    // transposed per-head: vt[((b*H+h)*64 + dd) * S + s], 8 consecutive s per store
    u16* Y = (u16*)Yv;
    const int mrow = m0 + ty * 8;
    const int bidx = mrow >> 11, s0v = mrow & (S_ - 1);
    const int hh = n0 >> 6;
#pragma unroll
    for (int j = 0; j < 4; ++j) {
      const int dd = tx * 4 + j;
      u16x8 o;
#pragma unroll
      for (int i = 0; i < 8; ++i) o[i] = f32_to_bf16(acc[i][j] + bb[j]);
      *(u16x8*)&Y[(((size_t)bidx * H_ + hh) * 64 + dd) * S_ + s0v] = o;
    }
  }
}

// ---------------------------------------------------------------------------
// Flash attention, bf16 MFMA (16x16x32), fp32 softmax+accum.
// Block: 64 q-rows of one (b,h), 4 waves x 16 q-rows. KV tile 64 keys.
// Q in registers; K row-major LDS; V^T tile from pre-transposed global vt;
// P bounced via per-wave LDS as bf16.
// MFMA layouts (guide-verified): A/B lane=row(l&15), k=(l>>4)*8+e contiguous;
// C/D col=l&15, row=(l>>4)*4+reg.
// ---------------------------------------------------------------------------
constexpr int LD = 88;   // LDS row stride (176B = 11*16B: aligned, bank-spread)

__global__ __launch_bounds__(256) void attn_mfma(
    const u16* __restrict__ qp, const u16* __restrict__ kp,
    const u16* __restrict__ vt, const int* __restrict__ mask,
    float* __restrict__ op)
{
  const int b = blockIdx.z, h = blockIdx.y;
  const int q0 = blockIdx.x * 64;
  const int tid = threadIdx.x;
  const int lane = tid & 63;
  const int w = tid >> 6;
  const int l15 = lane & 15, lg = lane >> 4;

  __shared__ u16 Ks[64][LD];        // [key][d]
  __shared__ u16 Vs[64][LD];        // [d][key]  (from global V^T)
  __shared__ u16 Pl[4][16][LD];     // per-wave P [q_local][key]

  const int qr = q0 + w * 16;

  // Q fragments, held for the whole kernel
  const u16* qrow = qp + ((size_t)b * S_ + qr + l15) * D_ + h * HD_;
  const s16x8 qf0 = *(const s16x8*)(qrow + lg * 8);
  const s16x8 qf1 = *(const s16x8*)(qrow + 32 + lg * 8);

  f32x4 out[4];
  float m_s[4], l_s[4];
#pragma unroll
  for (int dt = 0; dt < 4; ++dt) out[dt] = (f32x4){0.f, 0.f, 0.f, 0.f};
#pragma unroll
  for (int r = 0; r < 4; ++r) { m_s[r] = -3.0e38f; l_s[r] = 0.f; }

  // staging: thread -> row sr (0..63), col chunk sc (0/16/32/48), 2x16B each
  const int sr = tid >> 2;
  const int sc = (tid & 3) * 16;
  const u16* kbase = kp + (size_t)b * S_ * D_ + h * HD_;
  const u16* vbase = vt + (((size_t)b * H_ + h) * 64 + sr) * (size_t)S_;
  const int* mbase = mask + ((size_t)b * S_ + qr + lg * 4) * S_ + l15;

#pragma unroll 1
  for (int kt = 0; kt < S_; kt += 64) {
    // mask prefetch (16 ints, long-latency, overlap with staging)
    int mk[4][4];
#pragma unroll
    for (int r = 0; r < 4; ++r)
#pragma unroll
      for (int t = 0; t < 4; ++t)
        mk[r][t] = mbase[(size_t)r * S_ + kt + t * 16];

    __syncthreads();   // everyone done reading previous K/V tile
    {
      const u16* ksrc = kbase + (size_t)(kt + sr) * D_ + sc;
      uint4 k0 = *(const uint4*)(ksrc);
      uint4 k1 = *(const uint4*)(ksrc + 8);
      uint4 v0 = *(const uint4*)(vbase + kt + sc);
      uint4 v1 = *(const uint4*)(vbase + kt + sc + 8);
      *(uint4*)&Ks[sr][sc] = k0;
      *(uint4*)&Ks[sr][sc + 8] = k1;
      *(uint4*)&Vs[sr][sc] = v0;
      *(uint4*)&Vs[sr][sc + 8] = v1;
    }
    __syncthreads();

    // ---- QK^T: 4 key-tiles x 2 d-steps ----
    f32x4 sacc[4];
#pragma unroll
    for (int t = 0; t < 4; ++t) {
      s16x8 kb0 = *(const s16x8*)&Ks[t * 16 + l15][lg * 8];
      s16x8 kb1 = *(const s16x8*)&Ks[t * 16 + l15][32 + lg * 8];
      f32x4 z = (f32x4){0.f, 0.f, 0.f, 0.f};
      z = __builtin_amdgcn_mfma_f32_16x16x32_bf16(qf0, kb0, z, 0, 0, 0);
      z = __builtin_amdgcn_mfma_f32_16x16x32_bf16(qf1, kb1, z, 0, 0, 0);
      sacc[t] = z;
    }

    // ---- online softmax (row = lg*4+r; cols t*16+l15 across lanes) ----
    float corr_[4], p[4][4];
#pragma unroll
    for (int r = 0; r < 4; ++r) {
      float x0 = mk[r][0] ? sacc[0][r] * 0.125f : -1.0e9f;
      float x1 = mk[r][1] ? sacc[1][r] * 0.125f : -1.0e9f;
      float x2 = mk[r][2] ? sacc[2][r] * 0.125f : -1.0e9f;
      float x3 = mk[r][3] ? sacc[3][r] * 0.125f : -1.0e9f;
      float mx = fmaxf(fmaxf(x0, x1), fmaxf(x2, x3));
#pragma unroll
      for (int off = 1; off <= 8; off <<= 1)
        mx = fmaxf(mx, __shfl_xor(mx, off, 64));
      float mnew = fmaxf(m_s[r], mx);
      float c = exp2f((m_s[r] - mnew) * 1.44269504f);
      m_s[r] = mnew;
      float p0 = exp2f((x0 - mnew) * 1.44269504f);
      float p1 = exp2f((x1 - mnew) * 1.44269504f);
      float p2 = exp2f((x2 - mnew) * 1.44269504f);
      float p3 = exp2f((x3 - mnew) * 1.44269504f);
      float ps = (p0 + p1) + (p2 + p3);
#pragma unroll
      for (int off = 1; off <= 8; off <<= 1)
        ps += __shfl_xor(ps, off, 64);
      l_s[r] = l_s[r] * c + ps;
      corr_[r] = c;
      p[r][0] = p0; p[r][1] = p1; p[r][2] = p2; p[r][3] = p3;
    }

    // rescale output accumulators
#pragma unroll
    for (int dt = 0; dt < 4; ++dt)
#pragma unroll
      for (int r = 0; r < 4; ++r)
        out[dt][r] *= corr_[r];

    // P -> per-wave LDS (bf16). Same-wave write->read: DS pipe is in-order.
#pragma unroll
    for (int r = 0; r < 4; ++r)
#pragma unroll
      for (int t = 0; t < 4; ++t)
        Pl[w][lg * 4 + r][t * 16 + l15] = f32_to_bf16(p[r][t]);

    // ---- PV: out[q][d] += P[16q x 64k] @ V[64k x 64d] ----
    s16x8 pa0 = *(const s16x8*)&Pl[w][l15][lg * 8];
    s16x8 pa1 = *(const s16x8*)&Pl[w][l15][32 + lg * 8];
#pragma unroll
    for (int dt = 0; dt < 4; ++dt) {
      s16x8 vb0 = *(const s16x8*)&Vs[dt * 16 + l15][lg * 8];
      s16x8 vb1 = *(const s16x8*)&Vs[dt * 16 + l15][32 + lg * 8];
      out[dt] = __builtin_amdgcn_mfma_f32_16x16x32_bf16(pa0, vb0, out[dt], 0, 0, 0);
      out[dt] = __builtin_amdgcn_mfma_f32_16x16x32_bf16(pa1, vb1, out[dt], 0, 0, 0);
    }
  }

  // epilogue: op[b, qr+row, h*64 + dt*16 + l15] = out/l
#pragma unroll
  for (int r = 0; r < 4; ++r) {
    float inv = 1.0f / l_s[r];
#pragma unroll
    for (int dt = 0; dt < 4; ++dt)
      op[((size_t)b * S_ + qr + lg * 4 + r) * D_ + h * HD_ + dt * 16 + l15] =
          out[dt][r] * inv;
  }
}

// ---------------------------------------------------------------------------
extern "C" void kernel_launch(void* const* d_in, const int* in_sizes, int n_in,
                              void* d_out, int out_size, void* d_ws,
                              size_t ws_size, hipStream_t stream)
{
  const float* q_in = (const float*)d_in[0];
  const float* k_in = (const float*)d_in[1];
  const float* v_in = (const float*)d_in[2];
  const int*   mask = (const int*)d_in[3];
  const float* W1 = (const float*)d_in[4];
  const float* b1 = (const float*)d_in[5];
  const float* W2 = (const float*)d_in[6];
  const float* b2 = (const float*)d_in[7];
  const float* W3 = (const float*)d_in[8];
  const float* b3 = (const float*)d_in[9];
  const float* Wo = (const float*)d_in[10];
  const float* bo = (const float*)d_in[11];
  float* out = (float*)d_out;

  // workspace: qp/kp bf16 [M][D] (4MB each), vt bf16 [B*H*64][S] (4MB), op fp32 (8MB)
  u16* qp = (u16*)d_ws;
  u16* kp = qp + (size_t)M_ * D_;
  u16* vtp = kp + (size_t)M_ * D_;
  float* op = (float*)(vtp + (size_t)M_ * D_);

  dim3 blk(256);
  dim3 ggrid(M_ / GBM, D_ / GBN);
  gemm_xwT<1><<<ggrid, blk, 0, stream>>>(q_in, W1, b1, qp);
  gemm_xwT<1><<<ggrid, blk, 0, stream>>>(k_in, W2, b2, kp);
  gemm_xwT<2><<<ggrid, blk, 0, stream>>>(v_in, W3, b3, vtp);
  attn_mfma<<<dim3(S_ / 64, H_, B_), blk, 0, stream>>>(qp, kp, vtp, mask, op);
  gemm_xwT<0><<<ggrid, blk, 0, stream>>>(op, Wo, bo, out);
}

// Round 3
// 146.376 us; speedup vs baseline: 10.5982x; 1.8524x over previous
//
#include <hip/hip_runtime.h>
#include <math.h>

// MultiHeadAttention: B=2, S=2048, D=512, H=8, HD=64
constexpr int B_ = 2, S_ = 2048, D_ = 512, H_ = 8, HD_ = 64;
constexpr int M_ = B_ * S_;

typedef short s16x8 __attribute__((ext_vector_type(8)));    // 8 bf16 (A/B frag)
typedef float f32x4 __attribute__((ext_vector_type(4)));    // C/D frag
typedef unsigned short u16;

static __device__ __forceinline__ u16 f32_to_bf16(float f) {
  union { float f; unsigned int u; } v; v.f = f;
  unsigned int u = v.u;
  unsigned int r = (u + 0x7FFFu + ((u >> 16) & 1u)) >> 16;   // RNE
  return (u16)r;
}
static __device__ __forceinline__ unsigned int pack2(float lo, float hi) {
  return (unsigned int)f32_to_bf16(lo) | ((unsigned int)f32_to_bf16(hi) << 16);
}
static __device__ __forceinline__ uint4 pack8(float4 a, float4 b) {
  uint4 r;
  r.x = pack2(a.x, a.y); r.y = pack2(a.z, a.w);
  r.z = pack2(b.x, b.y); r.w = pack2(b.z, b.w);
  return r;
}

// ---------------------------------------------------------------------------
// bf16-MFMA GEMM: Y = X @ W^T + bias.  X:[M,512] (fp32 or bf16 per INBF16),
// W:[512,512] fp32 row-major (converted to bf16 during staging), fp32 accum.
// Tile 64x64, BK=64, 256 thr = 4 waves in 2x2, each wave a 32x32 sub-tile.
// LDS stride 72 u16 (144B): row bank rotation of 4 -> conflict-free b128.
// MODE 0: fp32 out [M][D]; MODE 1: bf16 out [M][D];
// MODE 2: bf16 out per-head transposed vt[((b*H+h)*64+dd)][s] via LDS transpose.
// ---------------------------------------------------------------------------
template <int MODE, bool INBF16>
__global__ __launch_bounds__(256) void gemm_bf16(
    const void* __restrict__ Xv, const float* __restrict__ W,
    const float* __restrict__ bias, void* __restrict__ Yv)
{
  __shared__ u16 As[64][72];
  __shared__ u16 Bs[64][72];

  const int tid = threadIdx.x;
  const int lane = tid & 63, w = tid >> 6;
  const int l15 = lane & 15, lg = lane >> 4;
  const int wm = w >> 1, wn = w & 1;
  const int m0 = blockIdx.x * 64, n0 = blockIdx.y * 64;
  const int sr = tid >> 2, sc = (tid & 3) * 16;   // staging row / u16-col

  f32x4 acc[2][2];
#pragma unroll
  for (int i = 0; i < 2; ++i)
#pragma unroll
    for (int j = 0; j < 2; ++j) acc[i][j] = (f32x4){0.f, 0.f, 0.f, 0.f};

#pragma unroll 1
  for (int k0 = 0; k0 < D_; k0 += 64) {
    uint4 a0, a1;
    if (INBF16) {
      const u16* X = (const u16*)Xv;
      const uint4* src = (const uint4*)&X[(size_t)(m0 + sr) * D_ + k0 + sc];
      a0 = src[0]; a1 = src[1];
    } else {
      const float* X = (const float*)Xv;
      const float4* src = (const float4*)&X[(size_t)(m0 + sr) * D_ + k0 + sc];
      float4 f0 = src[0], f1 = src[1], f2 = src[2], f3 = src[3];
      a0 = pack8(f0, f1); a1 = pack8(f2, f3);
    }
    const float4* wsrc = (const float4*)&W[(size_t)(n0 + sr) * D_ + k0 + sc];
    float4 w0 = wsrc[0], w1 = wsrc[1], w2 = wsrc[2], w3 = wsrc[3];
    uint4 b0 = pack8(w0, w1), b1 = pack8(w2, w3);

    __syncthreads();   // previous iteration's frag reads complete
    *(uint4*)&As[sr][sc] = a0; *(uint4*)&As[sr][sc + 8] = a1;
    *(uint4*)&Bs[sr][sc] = b0; *(uint4*)&Bs[sr][sc + 8] = b1;
    __syncthreads();

#pragma unroll
    for (int kw = 0; kw < 2; ++kw) {
      s16x8 af0 = *(const s16x8*)&As[wm * 32 + l15][kw * 32 + lg * 8];
      s16x8 af1 = *(const s16x8*)&As[wm * 32 + 16 + l15][kw * 32 + lg * 8];
      s16x8 bf0 = *(const s16x8*)&Bs[wn * 32 + l15][kw * 32 + lg * 8];
      s16x8 bf1 = *(const s16x8*)&Bs[wn * 32 + 16 + l15][kw * 32 + lg * 8];
      acc[0][0] = __builtin_amdgcn_mfma_f32_16x16x32_bf16(af0, bf0, acc[0][0], 0, 0, 0);
      acc[0][1] = __builtin_amdgcn_mfma_f32_16x16x32_bf16(af0, bf1, acc[0][1], 0, 0, 0);
      acc[1][0] = __builtin_amdgcn_mfma_f32_16x16x32_bf16(af1, bf0, acc[1][0], 0, 0, 0);
      acc[1][1] = __builtin_amdgcn_mfma_f32_16x16x32_bf16(af1, bf1, acc[1][1], 0, 0, 0);
    }
  }

  float bias_v[2];
  bias_v[0] = bias[n0 + wn * 32 + l15];
  bias_v[1] = bias[n0 + wn * 32 + 16 + l15];

  if (MODE == 0) {
    float* Y = (float*)Yv;
#pragma unroll
    for (int am = 0; am < 2; ++am)
#pragma unroll
      for (int bn = 0; bn < 2; ++bn)
#pragma unroll
        for (int j = 0; j < 4; ++j) {
          const int row = m0 + wm * 32 + am * 16 + lg * 4 + j;
          const int col = n0 + wn * 32 + bn * 16 + l15;
          Y[(size_t)row * D_ + col] = acc[am][bn][j] + bias_v[bn];
        }
  } else if (MODE == 1) {
    u16* Y = (u16*)Yv;
#pragma unroll
    for (int am = 0; am < 2; ++am)
#pragma unroll
      for (int bn = 0; bn < 2; ++bn)
#pragma unroll
        for (int j = 0; j < 4; ++j) {
          const int row = m0 + wm * 32 + am * 16 + lg * 4 + j;
          const int col = n0 + wn * 32 + bn * 16 + l15;
          Y[(size_t)row * D_ + col] = f32_to_bf16(acc[am][bn][j] + bias_v[bn]);
        }
  } else {
    // V^T: LDS-transpose epilogue, coalesced stores along s.
    __syncthreads();   // all waves done reading As
    u16(*Ct)[72] = (u16(*)[72])As;
#pragma unroll
    for (int am = 0; am < 2; ++am)
#pragma unroll
      for (int bn = 0; bn < 2; ++bn) {
        const int dd = wn * 32 + bn * 16 + l15;
        const int sl = wm * 32 + am * 16 + lg * 4;
        ushort4 pk;
        pk.x = f32_to_bf16(acc[am][bn][0] + bias_v[bn]);
        pk.y = f32_to_bf16(acc[am][bn][1] + bias_v[bn]);
        pk.z = f32_to_bf16(acc[am][bn][2] + bias_v[bn]);
        pk.w = f32_to_bf16(acc[am][bn][3] + bias_v[bn]);
        *(ushort4*)&Ct[dd][sl] = pk;
      }
    __syncthreads();
    const int batch = m0 >> 11, sb = m0 & (S_ - 1);
    u16* vt = (u16*)Yv;
    uint4 c0 = *(uint4*)&Ct[sr][sc];
    uint4 c1 = *(uint4*)&Ct[sr][sc + 8];
    u16* dst = &vt[(((size_t)batch * H_ + blockIdx.y) * 64 + sr) * S_ + sb + sc];
    *(uint4*)dst = c0;
    *(uint4*)(dst + 8) = c1;
  }
}

// ---------------------------------------------------------------------------
// Flash attention, bf16 MFMA (16x16x32), fp32 softmax+accum. Unchanged from
// R2 except: epilogue writes bf16 (feeds the bf16-MFMA output projection).
// ---------------------------------------------------------------------------
constexpr int LD = 88;

__global__ __launch_bounds__(256) void attn_mfma(
    const u16* __restrict__ qp, const u16* __restrict__ kp,
    const u16* __restrict__ vt, const int* __restrict__ mask,
    u16* __restrict__ ob)
{
  const int b = blockIdx.z, h = blockIdx.y;
  const int q0 = blockIdx.x * 64;
  const int tid = threadIdx.x;
  const int lane = tid & 63;
  const int w = tid >> 6;
  const int l15 = lane & 15, lg = lane >> 4;

  __shared__ u16 Ks[64][LD];
  __shared__ u16 Vs[64][LD];
  __shared__ u16 Pl[4][16][LD];

  const int qr = q0 + w * 16;

  const u16* qrow = qp + ((size_t)b * S_ + qr + l15) * D_ + h * HD_;
  const s16x8 qf0 = *(const s16x8*)(qrow + lg * 8);
  const s16x8 qf1 = *(const s16x8*)(qrow + 32 + lg * 8);

  f32x4 out[4];
  float m_s[4], l_s[4];
#pragma unroll
  for (int dt = 0; dt < 4; ++dt) out[dt] = (f32x4){0.f, 0.f, 0.f, 0.f};
#pragma unroll
  for (int r = 0; r < 4; ++r) { m_s[r] = -3.0e38f; l_s[r] = 0.f; }

  const int sr = tid >> 2;
  const int sc = (tid & 3) * 16;
  const u16* kbase = kp + (size_t)b * S_ * D_ + h * HD_;
  const u16* vbase = vt + (((size_t)b * H_ + h) * 64 + sr) * (size_t)S_;
  const int* mbase = mask + ((size_t)b * S_ + qr + lg * 4) * S_ + l15;

#pragma unroll 1
  for (int kt = 0; kt < S_; kt += 64) {
    int mk[4][4];
#pragma unroll
    for (int r = 0; r < 4; ++r)
#pragma unroll
      for (int t = 0; t < 4; ++t)
        mk[r][t] = mbase[(size_t)r * S_ + kt + t * 16];

    __syncthreads();
    {
      const u16* ksrc = kbase + (size_t)(kt + sr) * D_ + sc;
      uint4 k0 = *(const uint4*)(ksrc);
      uint4 k1 = *(const uint4*)(ksrc + 8);
      uint4 v0 = *(const uint4*)(vbase + kt + sc);
      uint4 v1 = *(const uint4*)(vbase + kt + sc + 8);
      *(uint4*)&Ks[sr][sc] = k0;
      *(uint4*)&Ks[sr][sc + 8] = k1;
      *(uint4*)&Vs[sr][sc] = v0;
      *(uint4*)&Vs[sr][sc + 8] = v1;
    }
    __syncthreads();

    f32x4 sacc[4];
#pragma unroll
    for (int t = 0; t < 4; ++t) {
      s16x8 kb0 = *(const s16x8*)&Ks[t * 16 + l15][lg * 8];
      s16x8 kb1 = *(const s16x8*)&Ks[t * 16 + l15][32 + lg * 8];
      f32x4 z = (f32x4){0.f, 0.f, 0.f, 0.f};
      z = __builtin_amdgcn_mfma_f32_16x16x32_bf16(qf0, kb0, z, 0, 0, 0);
      z = __builtin_amdgcn_mfma_f32_16x16x32_bf16(qf1, kb1, z, 0, 0, 0);
      sacc[t] = z;
    }

    float corr_[4], p[4][4];
#pragma unroll
    for (int r = 0; r < 4; ++r) {
      float x0 = mk[r][0] ? sacc[0][r] * 0.125f : -1.0e9f;
      float x1 = mk[r][1] ? sacc[1][r] * 0.125f : -1.0e9f;
      float x2 = mk[r][2] ? sacc[2][r] * 0.125f : -1.0e9f;
      float x3 = mk[r][3] ? sacc[3][r] * 0.125f : -1.0e9f;
      float mx = fmaxf(fmaxf(x0, x1), fmaxf(x2, x3));
#pragma unroll
      for (int off = 1; off <= 8; off <<= 1)
        mx = fmaxf(mx, __shfl_xor(mx, off, 64));
      float mnew = fmaxf(m_s[r], mx);
      float c = exp2f((m_s[r] - mnew) * 1.44269504f);
      m_s[r] = mnew;
      float p0 = exp2f((x0 - mnew) * 1.44269504f);
      float p1 = exp2f((x1 - mnew) * 1.44269504f);
      float p2 = exp2f((x2 - mnew) * 1.44269504f);
      float p3 = exp2f((x3 - mnew) * 1.44269504f);
      float ps = (p0 + p1) + (p2 + p3);
#pragma unroll
      for (int off = 1; off <= 8; off <<= 1)
        ps += __shfl_xor(ps, off, 64);
      l_s[r] = l_s[r] * c + ps;
      corr_[r] = c;
      p[r][0] = p0; p[r][1] = p1; p[r][2] = p2; p[r][3] = p3;
    }

#pragma unroll
    for (int dt = 0; dt < 4; ++dt)
#pragma unroll
      for (int r = 0; r < 4; ++r)
        out[dt][r] *= corr_[r];

#pragma unroll
    for (int r = 0; r < 4; ++r)
#pragma unroll
      for (int t = 0; t < 4; ++t)
        Pl[w][lg * 4 + r][t * 16 + l15] = f32_to_bf16(p[r][t]);

    s16x8 pa0 = *(const s16x8*)&Pl[w][l15][lg * 8];
    s16x8 pa1 = *(const s16x8*)&Pl[w][l15][32 + lg * 8];
#pragma unroll
    for (int dt = 0; dt < 4; ++dt) {
      s16x8 vb0 = *(const s16x8*)&Vs[dt * 16 + l15][lg * 8];
      s16x8 vb1 = *(const s16x8*)&Vs[dt * 16 + l15][32 + lg * 8];
      out[dt] = __builtin_amdgcn_mfma_f32_16x16x32_bf16(pa0, vb0, out[dt], 0, 0, 0);
      out[dt] = __builtin_amdgcn_mfma_f32_16x16x32_bf16(pa1, vb1, out[dt], 0, 0, 0);
    }
  }

#pragma unroll
  for (int r = 0; r < 4; ++r) {
    float inv = 1.0f / l_s[r];
#pragma unroll
    for (int dt = 0; dt < 4; ++dt)
      ob[((size_t)b * S_ + qr + lg * 4 + r) * D_ + h * HD_ + dt * 16 + l15] =
          f32_to_bf16(out[dt][r] * inv);
  }
}

// ---------------------------------------------------------------------------
extern "C" void kernel_launch(void* const* d_in, const int* in_sizes, int n_in,
                              void* d_out, int out_size, void* d_ws,
                              size_t ws_size, hipStream_t stream)
{
  const float* q_in = (const float*)d_in[0];
  const float* k_in = (const float*)d_in[1];
  const float* v_in = (const float*)d_in[2];
  const int*   mask = (const int*)d_in[3];
  const float* W1 = (const float*)d_in[4];
  const float* b1 = (const float*)d_in[5];
  const float* W2 = (const float*)d_in[6];
  const float* b2 = (const float*)d_in[7];
  const float* W3 = (const float*)d_in[8];
  const float* b3 = (const float*)d_in[9];
  const float* Wo = (const float*)d_in[10];
  const float* bo = (const float*)d_in[11];
  float* out = (float*)d_out;

  // workspace (bf16): qp, kp [M][D]; vt [B*H*64][S]; ob [M][D]  (4 x 4MB)
  u16* qp = (u16*)d_ws;
  u16* kp = qp + (size_t)M_ * D_;
  u16* vtp = kp + (size_t)M_ * D_;
  u16* ob = vtp + (size_t)M_ * D_;

  dim3 blk(256);
  dim3 ggrid(M_ / 64, D_ / 64);   // 64 x 8 = 512 WGs
  gemm_bf16<1, false><<<ggrid, blk, 0, stream>>>(q_in, W1, b1, qp);
  gemm_bf16<1, false><<<ggrid, blk, 0, stream>>>(k_in, W2, b2, kp);
  gemm_bf16<2, false><<<ggrid, blk, 0, stream>>>(v_in, W3, b3, vtp);
  attn_mfma<<<dim3(S_ / 64, H_, B_), blk, 0, stream>>>(qp, kp, vtp, mask, ob);
  gemm_bf16<0, true><<<ggrid, blk, 0, stream>>>(ob, Wo, bo, out);
}

// Round 4
// 124.242 us; speedup vs baseline: 12.4863x; 1.1782x over previous
//
#include <hip/hip_runtime.h>
#include <math.h>

// MultiHeadAttention: B=2, S=2048, D=512, H=8, HD=64
constexpr int B_ = 2, S_ = 2048, D_ = 512, H_ = 8, HD_ = 64;
constexpr int M_ = B_ * S_;
constexpr int NT_ = S_ / 64;          // 32 key tiles / mask u64 slots per row

typedef short s16x8 __attribute__((ext_vector_type(8)));    // 8 bf16 (A/B frag)
typedef float f32x4 __attribute__((ext_vector_type(4)));    // C/D frag
typedef unsigned short u16;
typedef unsigned long long u64;

static __device__ __forceinline__ u16 f32_to_bf16(float f) {
  union { float f; unsigned int u; } v; v.f = f;
  unsigned int u = v.u;
  unsigned int r = (u + 0x7FFFu + ((u >> 16) & 1u)) >> 16;   // RNE
  return (u16)r;
}
static __device__ __forceinline__ unsigned int pack2(float lo, float hi) {
  return (unsigned int)f32_to_bf16(lo) | ((unsigned int)f32_to_bf16(hi) << 16);
}
static __device__ __forceinline__ uint4 pack8(float4 a, float4 b) {
  uint4 r;
  r.x = pack2(a.x, a.y); r.y = pack2(a.z, a.w);
  r.z = pack2(b.x, b.y); r.w = pack2(b.z, b.w);
  return r;
}

// ---------------------------------------------------------------------------
// Mask int32 -> packed bits: mbits[b*S + q][tile] = ballot of 64 keys.
// ---------------------------------------------------------------------------
__global__ __launch_bounds__(256) void mask_pack(
    const int* __restrict__ mask, u64* __restrict__ mbits)
{
  const int lane = threadIdx.x & 63;
  const int wid = (blockIdx.x * blockDim.x + threadIdx.x) >> 6;
  const int nw = (gridDim.x * blockDim.x) >> 6;
  const int nslots = B_ * S_ * NT_;
  for (int s = wid; s < nslots; s += nw) {
    int v = mask[(size_t)s * 64 + lane];
    u64 bits = __ballot(v != 0);
    if (lane == 0) mbits[s] = bits;
  }
}

// ---------------------------------------------------------------------------
// Fused QKV projection: Y = X @ W^T + bias, bf16-MFMA, fp32 accum.
// blockIdx.z selects (X,W,b,Y); z==2 (V) writes per-head-transposed vt.
// Tile 64x64, BK=64, 4 waves 2x2.
// ---------------------------------------------------------------------------
__global__ __launch_bounds__(256) void gemm_qkv(
    const float* __restrict__ Xq, const float* __restrict__ Wq,
    const float* __restrict__ bq, u16* __restrict__ Yq,
    const float* __restrict__ Xk, const float* __restrict__ Wk,
    const float* __restrict__ bk, u16* __restrict__ Yk,
    const float* __restrict__ Xv, const float* __restrict__ Wv,
    const float* __restrict__ bv, u16* __restrict__ Yv)
{
  const float* X; const float* W; const float* bias; u16* Y;
  const int z = blockIdx.z;
  if (z == 0)      { X = Xq; W = Wq; bias = bq; Y = Yq; }
  else if (z == 1) { X = Xk; W = Wk; bias = bk; Y = Yk; }
  else             { X = Xv; W = Wv; bias = bv; Y = Yv; }

  __shared__ u16 As[64][72];
  __shared__ u16 Bs[64][72];

  const int tid = threadIdx.x;
  const int lane = tid & 63, w = tid >> 6;
  const int l15 = lane & 15, lg = lane >> 4;
  const int wm = w >> 1, wn = w & 1;
  const int m0 = blockIdx.x * 64, n0 = blockIdx.y * 64;
  const int sr = tid >> 2, sc = (tid & 3) * 16;

  f32x4 acc[2][2];
#pragma unroll
  for (int i = 0; i < 2; ++i)
#pragma unroll
    for (int j = 0; j < 2; ++j) acc[i][j] = (f32x4){0.f, 0.f, 0.f, 0.f};

#pragma unroll 1
  for (int k0 = 0; k0 < D_; k0 += 64) {
    const float4* src = (const float4*)&X[(size_t)(m0 + sr) * D_ + k0 + sc];
    float4 f0 = src[0], f1 = src[1], f2 = src[2], f3 = src[3];
    uint4 a0 = pack8(f0, f1), a1 = pack8(f2, f3);
    const float4* wsrc = (const float4*)&W[(size_t)(n0 + sr) * D_ + k0 + sc];
    float4 w0 = wsrc[0], w1 = wsrc[1], w2 = wsrc[2], w3 = wsrc[3];
    uint4 b0 = pack8(w0, w1), b1 = pack8(w2, w3);

    __syncthreads();
    *(uint4*)&As[sr][sc] = a0; *(uint4*)&As[sr][sc + 8] = a1;
    *(uint4*)&Bs[sr][sc] = b0; *(uint4*)&Bs[sr][sc + 8] = b1;
    __syncthreads();

#pragma unroll
    for (int kw = 0; kw < 2; ++kw) {
      s16x8 af0 = *(const s16x8*)&As[wm * 32 + l15][kw * 32 + lg * 8];
      s16x8 af1 = *(const s16x8*)&As[wm * 32 + 16 + l15][kw * 32 + lg * 8];
      s16x8 bf0 = *(const s16x8*)&Bs[wn * 32 + l15][kw * 32 + lg * 8];
      s16x8 bf1 = *(const s16x8*)&Bs[wn * 32 + 16 + l15][kw * 32 + lg * 8];
      acc[0][0] = __builtin_amdgcn_mfma_f32_16x16x32_bf16(af0, bf0, acc[0][0], 0, 0, 0);
      acc[0][1] = __builtin_amdgcn_mfma_f32_16x16x32_bf16(af0, bf1, acc[0][1], 0, 0, 0);
      acc[1][0] = __builtin_amdgcn_mfma_f32_16x16x32_bf16(af1, bf0, acc[1][0], 0, 0, 0);
      acc[1][1] = __builtin_amdgcn_mfma_f32_16x16x32_bf16(af1, bf1, acc[1][1], 0, 0, 0);
    }
  }

  float bias_v[2];
  bias_v[0] = bias[n0 + wn * 32 + l15];
  bias_v[1] = bias[n0 + wn * 32 + 16 + l15];

  if (z != 2) {
#pragma unroll
    for (int am = 0; am < 2; ++am)
#pragma unroll
      for (int bn = 0; bn < 2; ++bn)
#pragma unroll
        for (int j = 0; j < 4; ++j) {
          const int row = m0 + wm * 32 + am * 16 + lg * 4 + j;
          const int col = n0 + wn * 32 + bn * 16 + l15;
          Y[(size_t)row * D_ + col] = f32_to_bf16(acc[am][bn][j] + bias_v[bn]);
        }
  } else {
    // V^T epilogue: LDS transpose, coalesced along s.
    __syncthreads();
    u16(*Ct)[72] = (u16(*)[72])As;
#pragma unroll
    for (int am = 0; am < 2; ++am)
#pragma unroll
      for (int bn = 0; bn < 2; ++bn) {
        const int dd = wn * 32 + bn * 16 + l15;
        const int sl = wm * 32 + am * 16 + lg * 4;
        ushort4 pk;
        pk.x = f32_to_bf16(acc[am][bn][0] + bias_v[bn]);
        pk.y = f32_to_bf16(acc[am][bn][1] + bias_v[bn]);
        pk.z = f32_to_bf16(acc[am][bn][2] + bias_v[bn]);
        pk.w = f32_to_bf16(acc[am][bn][3] + bias_v[bn]);
        *(ushort4*)&Ct[dd][sl] = pk;
      }
    __syncthreads();
    const int batch = m0 >> 11, sb = m0 & (S_ - 1);
    uint4 c0 = *(uint4*)&Ct[sr][sc];
    uint4 c1 = *(uint4*)&Ct[sr][sc + 8];
    u16* dst = &Y[(((size_t)batch * H_ + blockIdx.y) * 64 + sr) * S_ + sb + sc];
    *(uint4*)dst = c0;
    *(uint4*)(dst + 8) = c1;
  }
}

// ---------------------------------------------------------------------------
// Out projection: Y = X(bf16) @ W^T + bias -> fp32. Same 64x64 structure.
// ---------------------------------------------------------------------------
__global__ __launch_bounds__(256) void gemm_oproj(
    const u16* __restrict__ X, const float* __restrict__ W,
    const float* __restrict__ bias, float* __restrict__ Y)
{
  __shared__ u16 As[64][72];
  __shared__ u16 Bs[64][72];

  const int tid = threadIdx.x;
  const int lane = tid & 63, w = tid >> 6;
  const int l15 = lane & 15, lg = lane >> 4;
  const int wm = w >> 1, wn = w & 1;
  const int m0 = blockIdx.x * 64, n0 = blockIdx.y * 64;
  const int sr = tid >> 2, sc = (tid & 3) * 16;

  f32x4 acc[2][2];
#pragma unroll
  for (int i = 0; i < 2; ++i)
#pragma unroll
    for (int j = 0; j < 2; ++j) acc[i][j] = (f32x4){0.f, 0.f, 0.f, 0.f};

#pragma unroll 1
  for (int k0 = 0; k0 < D_; k0 += 64) {
    const uint4* src = (const uint4*)&X[(size_t)(m0 + sr) * D_ + k0 + sc];
    uint4 a0 = src[0], a1 = src[1];
    const float4* wsrc = (const float4*)&W[(size_t)(n0 + sr) * D_ + k0 + sc];
    float4 w0 = wsrc[0], w1 = wsrc[1], w2 = wsrc[2], w3 = wsrc[3];
    uint4 b0 = pack8(w0, w1), b1 = pack8(w2, w3);

    __syncthreads();
    *(uint4*)&As[sr][sc] = a0; *(uint4*)&As[sr][sc + 8] = a1;
    *(uint4*)&Bs[sr][sc] = b0; *(uint4*)&Bs[sr][sc + 8] = b1;
    __syncthreads();

#pragma unroll
    for (int kw = 0; kw < 2; ++kw) {
      s16x8 af0 = *(const s16x8*)&As[wm * 32 + l15][kw * 32 + lg * 8];
      s16x8 af1 = *(const s16x8*)&As[wm * 32 + 16 + l15][kw * 32 + lg * 8];
      s16x8 bf0 = *(const s16x8*)&Bs[wn * 32 + l15][kw * 32 + lg * 8];
      s16x8 bf1 = *(const s16x8*)&Bs[wn * 32 + 16 + l15][kw * 32 + lg * 8];
      acc[0][0] = __builtin_amdgcn_mfma_f32_16x16x32_bf16(af0, bf0, acc[0][0], 0, 0, 0);
      acc[0][1] = __builtin_amdgcn_mfma_f32_16x16x32_bf16(af0, bf1, acc[0][1], 0, 0, 0);
      acc[1][0] = __builtin_amdgcn_mfma_f32_16x16x32_bf16(af1, bf0, acc[1][0], 0, 0, 0);
      acc[1][1] = __builtin_amdgcn_mfma_f32_16x16x32_bf16(af1, bf1, acc[1][1], 0, 0, 0);
    }
  }

  float bias_v[2];
  bias_v[0] = bias[n0 + wn * 32 + l15];
  bias_v[1] = bias[n0 + wn * 32 + 16 + l15];
#pragma unroll
  for (int am = 0; am < 2; ++am)
#pragma unroll
    for (int bn = 0; bn < 2; ++bn)
#pragma unroll
      for (int j = 0; j < 4; ++j) {
        const int row = m0 + wm * 32 + am * 16 + lg * 4 + j;
        const int col = n0 + wn * 32 + bn * 16 + l15;
        Y[(size_t)row * D_ + col] = acc[am][bn][j] + bias_v[bn];
      }
}

// ---------------------------------------------------------------------------
// Flash attention, swapped-operand MFMA + in-register softmax.
// QK^T = mfma(K, Q): lane holds S[key = t*16+lg*4+r][q = l15] -> per-lane
// full q-row ownership (m, l are per-lane scalars; reduce = in-lane + 2 shfl).
// PV = mfma(V, P): D[d = dt*16+lg*4+r][q = l15] -> rescale is lane-local.
// P bounced via per-wave XOR-swizzled LDS (4x ds_write_b64 + 2x ds_read_b128).
// Mask from packed bits (1x 8B load per lane per tile).
// ---------------------------------------------------------------------------
constexpr int LD = 88;
constexpr float SCL = 0.18033688f;   // (1/sqrt(64)) * log2(e); softmax in log2 domain

__global__ __launch_bounds__(256) void attn_mfma(
    const u16* __restrict__ qp, const u16* __restrict__ kp,
    const u16* __restrict__ vt, const u64* __restrict__ mbits,
    u16* __restrict__ ob)
{
  const int b = blockIdx.z, h = blockIdx.y;
  const int q0 = blockIdx.x * 64;
  const int tid = threadIdx.x;
  const int lane = tid & 63;
  const int w = tid >> 6;
  const int l15 = lane & 15, lg = lane >> 4;

  __shared__ u16 Ks[64][LD];        // [key][d]
  __shared__ u16 Vs[64][LD];        // [d][key] (V^T)
  __shared__ u16 Pl[4][16][64];     // per-wave P [q=l15][key], XOR-swizzled

  const int qr = q0 + w * 16;

  // Q fragments (B-operand: rows = q = l15)
  const u16* qrow = qp + ((size_t)b * S_ + qr + l15) * D_ + h * HD_;
  const s16x8 qf0 = *(const s16x8*)(qrow + lg * 8);
  const s16x8 qf1 = *(const s16x8*)(qrow + 32 + lg * 8);

  f32x4 out[4];
#pragma unroll
  for (int dt = 0; dt < 4; ++dt) out[dt] = (f32x4){0.f, 0.f, 0.f, 0.f};
  float m_s = -3.0e38f, l_s = 0.f;   // per-lane stats for q-row l15 (log2 dom.)

  const int sr = tid >> 2;
  const int sc = (tid & 3) * 16;
  const u16* kbase = kp + (size_t)b * S_ * D_ + h * HD_;
  const u16* vbase = vt + (((size_t)b * H_ + h) * 64 + sr) * (size_t)S_;
  const u64* mrow = mbits + ((size_t)b * S_ + qr + l15) * NT_;

  char* pw = (char*)&Pl[w][0][0];
  const int swz = (l15 & 3) << 5;

#pragma unroll 1
  for (int kt = 0; kt < S_; kt += 64) {
    u64 sh = mrow[kt >> 6] >> (lg * 4);   // bit (t*16+r) = key t*16+lg*4+r

    __syncthreads();
    {
      const u16* ksrc = kbase + (size_t)(kt + sr) * D_ + sc;
      uint4 k0 = *(const uint4*)(ksrc);
      uint4 k1 = *(const uint4*)(ksrc + 8);
      uint4 v0 = *(const uint4*)(vbase + kt + sc);
      uint4 v1 = *(const uint4*)(vbase + kt + sc + 8);
      *(uint4*)&Ks[sr][sc] = k0;
      *(uint4*)&Ks[sr][sc + 8] = k1;
      *(uint4*)&Vs[sr][sc] = v0;
      *(uint4*)&Vs[sr][sc + 8] = v1;
    }
    __syncthreads();

    // ---- QK^T (swapped): z[t][r] = S[t*16+lg*4+r][l15] ----
    f32x4 z[4];
    __builtin_amdgcn_s_setprio(1);
#pragma unroll
    for (int t = 0; t < 4; ++t) {
      s16x8 kb0 = *(const s16x8*)&Ks[t * 16 + l15][lg * 8];
      s16x8 kb1 = *(const s16x8*)&Ks[t * 16 + l15][32 + lg * 8];
      f32x4 zz = (f32x4){0.f, 0.f, 0.f, 0.f};
      zz = __builtin_amdgcn_mfma_f32_16x16x32_bf16(kb0, qf0, zz, 0, 0, 0);
      zz = __builtin_amdgcn_mfma_f32_16x16x32_bf16(kb1, qf1, zz, 0, 0, 0);
      z[t] = zz;
    }
    __builtin_amdgcn_s_setprio(0);

    // ---- masked scale (log2 domain), in-lane + 2-shfl row max ----
    float x[4][4];
#pragma unroll
    for (int t = 0; t < 4; ++t) {
      unsigned int g = (unsigned int)(sh >> (t * 16)) & 0xFu;
#pragma unroll
      for (int r = 0; r < 4; ++r)
        x[t][r] = ((g >> r) & 1u) ? z[t][r] * SCL : -1.0e9f;
    }
    float mx = x[0][0];
#pragma unroll
    for (int t = 0; t < 4; ++t)
#pragma unroll
      for (int r = 0; r < 4; ++r) mx = fmaxf(mx, x[t][r]);
    mx = fmaxf(mx, __shfl_xor(mx, 16, 64));
    mx = fmaxf(mx, __shfl_xor(mx, 32, 64));
    const float mnew = fmaxf(m_s, mx);
    const float corr = exp2f(m_s - mnew);
    m_s = mnew;

    float ps = 0.f;
#pragma unroll
    for (int t = 0; t < 4; ++t)
#pragma unroll
      for (int r = 0; r < 4; ++r) {
        float p = exp2f(x[t][r] - mnew);
        x[t][r] = p;
        ps += p;
      }
    ps += __shfl_xor(ps, 16, 64);
    ps += __shfl_xor(ps, 32, 64);
    l_s = l_s * corr + ps;

    // ---- P -> per-wave swizzled LDS (bf16), 4x b64 ----
#pragma unroll
    for (int t = 0; t < 4; ++t) {
      uint2 pk;
      pk.x = pack2(x[t][0], x[t][1]);
      pk.y = pack2(x[t][2], x[t][3]);
      const int off = l15 * 128 + t * 32 + lg * 8;
      *(uint2*)(pw + (off ^ swz)) = pk;
    }

    // rescale accumulators (lane-local corr)
#pragma unroll
    for (int dt = 0; dt < 4; ++dt)
#pragma unroll
      for (int r = 0; r < 4; ++r) out[dt][r] *= corr;

    // ---- PV (swapped): A = V^T rows (d), B = P rows (q = l15) ----
    const int roff = l15 * 128 + lg * 16;
    s16x8 pa0 = *(const s16x8*)(pw + (roff ^ swz));
    s16x8 pa1 = *(const s16x8*)(pw + ((roff + 64) ^ swz));
    __builtin_amdgcn_s_setprio(1);
#pragma unroll
    for (int dt = 0; dt < 4; ++dt) {
      s16x8 va0 = *(const s16x8*)&Vs[dt * 16 + l15][lg * 8];
      s16x8 va1 = *(const s16x8*)&Vs[dt * 16 + l15][32 + lg * 8];
      out[dt] = __builtin_amdgcn_mfma_f32_16x16x32_bf16(va0, pa0, out[dt], 0, 0, 0);
      out[dt] = __builtin_amdgcn_mfma_f32_16x16x32_bf16(va1, pa1, out[dt], 0, 0, 0);
    }
    __builtin_amdgcn_s_setprio(0);
  }

  // epilogue: q = l15, d = dt*16 + lg*4 + r -> bf16
  const float inv = 1.0f / l_s;
  u16* obase = ob + ((size_t)b * S_ + qr + l15) * D_ + h * HD_;
#pragma unroll
  for (int dt = 0; dt < 4; ++dt) {
    ushort4 pk;
    pk.x = f32_to_bf16(out[dt][0] * inv);
    pk.y = f32_to_bf16(out[dt][1] * inv);
    pk.z = f32_to_bf16(out[dt][2] * inv);
    pk.w = f32_to_bf16(out[dt][3] * inv);
    *(ushort4*)&obase[dt * 16 + lg * 4] = pk;
  }
}

// ---------------------------------------------------------------------------
extern "C" void kernel_launch(void* const* d_in, const int* in_sizes, int n_in,
                              void* d_out, int out_size, void* d_ws,
                              size_t ws_size, hipStream_t stream)
{
  const float* q_in = (const float*)d_in[0];
  const float* k_in = (const float*)d_in[1];
  const float* v_in = (const float*)d_in[2];
  const int*   mask = (const int*)d_in[3];
  const float* W1 = (const float*)d_in[4];
  const float* b1 = (const float*)d_in[5];
  const float* W2 = (const float*)d_in[6];
  const float* b2 = (const float*)d_in[7];
  const float* W3 = (const float*)d_in[8];
  const float* b3 = (const float*)d_in[9];
  const float* Wo = (const float*)d_in[10];
  const float* bo = (const float*)d_in[11];
  float* out = (float*)d_out;

  // workspace: qp, kp [M][D] bf16; vt [B*H*64][S] bf16; ob [M][D] bf16; mbits
  u16* qp = (u16*)d_ws;
  u16* kp = qp + (size_t)M_ * D_;
  u16* vtp = kp + (size_t)M_ * D_;
  u16* ob = vtp + (size_t)M_ * D_;
  u64* mbits = (u64*)(ob + (size_t)M_ * D_);

  dim3 blk(256);
  mask_pack<<<512, blk, 0, stream>>>(mask, mbits);
  gemm_qkv<<<dim3(M_ / 64, D_ / 64, 3), blk, 0, stream>>>(
      q_in, W1, b1, qp, k_in, W2, b2, kp, v_in, W3, b3, vtp);
  attn_mfma<<<dim3(S_ / 64, H_, B_), blk, 0, stream>>>(qp, kp, vtp, mbits, ob);
  gemm_oproj<<<dim3(M_ / 64, D_ / 64), blk, 0, stream>>>(ob, Wo, bo, out);
}

// Round 6
// 121.587 us; speedup vs baseline: 12.7590x; 1.0218x over previous
//
#include <hip/hip_runtime.h>
#include <hip/hip_bf16.h>
#include <math.h>

// MultiHeadAttention: B=2, S=2048, D=512, H=8, HD=64
constexpr int B_ = 2, S_ = 2048, D_ = 512, H_ = 8, HD_ = 64;
constexpr int M_ = B_ * S_;
constexpr int NT_ = S_ / 64;          // 32 key tiles / mask u64 slots per row

typedef short s16x8 __attribute__((ext_vector_type(8)));    // 8 bf16 (A/B frag)
typedef float f32x4 __attribute__((ext_vector_type(4)));    // C/D frag
typedef unsigned short u16;
typedef unsigned long long u64;

// XOR swizzle for 128B-row LDS tiles: flips byte bits 4-6 by row&7.
// Involution; spreads the 16-rows-x-4-chunks b128 read pattern over all banks.
#define SWZ(b) ((b) ^ ((((b) >> 7) & 7) << 4))

static __device__ __forceinline__ unsigned int cvt_pk2(float lo, float hi) {
  __hip_bfloat162 h = __float22bfloat162_rn(make_float2(lo, hi));
  return *(unsigned int*)&h;
}
static __device__ __forceinline__ u16 cvt1(float f) {
  __hip_bfloat16 h = __float2bfloat16(f);
  return *(u16*)&h;
}
static __device__ __forceinline__ uint4 pack8(float4 a, float4 b) {
  uint4 r;
  r.x = cvt_pk2(a.x, a.y); r.y = cvt_pk2(a.z, a.w);
  r.z = cvt_pk2(b.x, b.y); r.w = cvt_pk2(b.z, b.w);
  return r;
}

// ---------------------------------------------------------------------------
// Mask int32 -> packed bits: mbits[b*S + q][tile] = ballot of 64 keys.
// ---------------------------------------------------------------------------
__global__ __launch_bounds__(256) void mask_pack(
    const int* __restrict__ mask, u64* __restrict__ mbits)
{
  const int lane = threadIdx.x & 63;
  const int wid = (blockIdx.x * blockDim.x + threadIdx.x) >> 6;
  const int nw = (gridDim.x * blockDim.x) >> 6;
  const int nslots = B_ * S_ * NT_;
  for (int s = wid; s < nslots; s += nw) {
    int v = mask[(size_t)s * 64 + lane];
    u64 bits = __ballot(v != 0);
    if (lane == 0) mbits[s] = bits;
  }
}

// ---------------------------------------------------------------------------
// Fused QKV projection: Y = X @ W^T + bias, bf16-MFMA, fp32 accum.
// blockIdx.z selects (X,W,b,Y); z==2 (V) writes per-head-transposed vt.
// Tile 64x64, BK=64, 4 waves 2x2. LDS: [2][64][64] u16, XOR-swizzled 128B rows.
// ---------------------------------------------------------------------------
__global__ __launch_bounds__(256) void gemm_qkv(
    const float* __restrict__ Xq, const float* __restrict__ Wq,
    const float* __restrict__ bq, u16* __restrict__ Yq,
    const float* __restrict__ Xk, const float* __restrict__ Wk,
    const float* __restrict__ bk, u16* __restrict__ Yk,
    const float* __restrict__ Xv, const float* __restrict__ Wv,
    const float* __restrict__ bv, u16* __restrict__ Yv)
{
  const float* X; const float* W; const float* bias; u16* Y;
  const int z = blockIdx.z;
  if (z == 0)      { X = Xq; W = Wq; bias = bq; Y = Yq; }
  else if (z == 1) { X = Xk; W = Wk; bias = bk; Y = Yk; }
  else             { X = Xv; W = Wv; bias = bv; Y = Yv; }

  __shared__ __align__(128) u16 SH[2][64][64];   // [A/B][row][col]
  char* shb = (char*)SH;

  const int tid = threadIdx.x;
  const int lane = tid & 63, w = tid >> 6;
  const int l15 = lane & 15, lg = lane >> 4;
  const int wm = w >> 1, wn = w & 1;
  const int m0 = blockIdx.x * 64, n0 = blockIdx.y * 64;
  const int sr = tid >> 2, sc = (tid & 3) * 16;

  f32x4 acc[2][2];
#pragma unroll
  for (int i = 0; i < 2; ++i)
#pragma unroll
    for (int j = 0; j < 2; ++j) acc[i][j] = (f32x4){0.f, 0.f, 0.f, 0.f};

#pragma unroll 1
  for (int k0 = 0; k0 < D_; k0 += 64) {
    const float4* src = (const float4*)&X[(size_t)(m0 + sr) * D_ + k0 + sc];
    float4 f0 = src[0], f1 = src[1], f2 = src[2], f3 = src[3];
    uint4 a0 = pack8(f0, f1), a1 = pack8(f2, f3);
    const float4* wsrc = (const float4*)&W[(size_t)(n0 + sr) * D_ + k0 + sc];
    float4 w0 = wsrc[0], w1 = wsrc[1], w2 = wsrc[2], w3 = wsrc[3];
    uint4 b0 = pack8(w0, w1), b1 = pack8(w2, w3);

    __syncthreads();
    {
      const int aw = (sr << 7) + (tid & 3) * 32;
      const int bw = ((64 + sr) << 7) + (tid & 3) * 32;
      *(uint4*)(shb + SWZ(aw)) = a0; *(uint4*)(shb + SWZ(aw + 16)) = a1;
      *(uint4*)(shb + SWZ(bw)) = b0; *(uint4*)(shb + SWZ(bw + 16)) = b1;
    }
    __syncthreads();

#pragma unroll
    for (int kw = 0; kw < 2; ++kw) {
      const int ar0 = ((wm * 32 + l15) << 7) + kw * 64 + lg * 16;
      const int ar1 = ((wm * 32 + 16 + l15) << 7) + kw * 64 + lg * 16;
      const int br0 = ((64 + wn * 32 + l15) << 7) + kw * 64 + lg * 16;
      const int br1 = ((64 + wn * 32 + 16 + l15) << 7) + kw * 64 + lg * 16;
      s16x8 af0 = *(const s16x8*)(shb + SWZ(ar0));
      s16x8 af1 = *(const s16x8*)(shb + SWZ(ar1));
      s16x8 bf0 = *(const s16x8*)(shb + SWZ(br0));
      s16x8 bf1 = *(const s16x8*)(shb + SWZ(br1));
      acc[0][0] = __builtin_amdgcn_mfma_f32_16x16x32_bf16(af0, bf0, acc[0][0], 0, 0, 0);
      acc[0][1] = __builtin_amdgcn_mfma_f32_16x16x32_bf16(af0, bf1, acc[0][1], 0, 0, 0);
      acc[1][0] = __builtin_amdgcn_mfma_f32_16x16x32_bf16(af1, bf0, acc[1][0], 0, 0, 0);
      acc[1][1] = __builtin_amdgcn_mfma_f32_16x16x32_bf16(af1, bf1, acc[1][1], 0, 0, 0);
    }
  }

  float bias_v[2];
  bias_v[0] = bias[n0 + wn * 32 + l15];
  bias_v[1] = bias[n0 + wn * 32 + 16 + l15];

  if (z != 2) {
#pragma unroll
    for (int am = 0; am < 2; ++am)
#pragma unroll
      for (int bn = 0; bn < 2; ++bn)
#pragma unroll
        for (int j = 0; j < 4; ++j) {
          const int row = m0 + wm * 32 + am * 16 + lg * 4 + j;
          const int col = n0 + wn * 32 + bn * 16 + l15;
          Y[(size_t)row * D_ + col] = cvt1(acc[am][bn][j] + bias_v[bn]);
        }
  } else {
    // V^T epilogue: swizzled LDS transpose, coalesced along s.
    __syncthreads();
#pragma unroll
    for (int am = 0; am < 2; ++am)
#pragma unroll
      for (int bn = 0; bn < 2; ++bn) {
        const int dd = wn * 32 + bn * 16 + l15;
        const int sl = wm * 32 + am * 16 + lg * 4;
        ushort4 pk;
        pk.x = cvt1(acc[am][bn][0] + bias_v[bn]);
        pk.y = cvt1(acc[am][bn][1] + bias_v[bn]);
        pk.z = cvt1(acc[am][bn][2] + bias_v[bn]);
        pk.w = cvt1(acc[am][bn][3] + bias_v[bn]);
        const int cw = (dd << 7) + sl * 2;
        *(ushort4*)(shb + SWZ(cw)) = pk;
      }
    __syncthreads();
    const int batch = m0 >> 11, sb = m0 & (S_ - 1);
    const int cr = (sr << 7) + (tid & 3) * 32;
    uint4 c0 = *(uint4*)(shb + SWZ(cr));
    uint4 c1 = *(uint4*)(shb + SWZ(cr + 16));
    u16* dst = &Y[(((size_t)batch * H_ + blockIdx.y) * 64 + sr) * S_ + sb + sc];
    *(uint4*)dst = c0;
    *(uint4*)(dst + 8) = c1;
  }
}

// ---------------------------------------------------------------------------
// Out projection: Y = X(bf16) @ W^T + bias -> fp32. Same swizzled structure.
// ---------------------------------------------------------------------------
__global__ __launch_bounds__(256) void gemm_oproj(
    const u16* __restrict__ X, const float* __restrict__ W,
    const float* __restrict__ bias, float* __restrict__ Y)
{
  __shared__ __align__(128) u16 SH[2][64][64];
  char* shb = (char*)SH;

  const int tid = threadIdx.x;
  const int lane = tid & 63, w = tid >> 6;
  const int l15 = lane & 15, lg = lane >> 4;
  const int wm = w >> 1, wn = w & 1;
  const int m0 = blockIdx.x * 64, n0 = blockIdx.y * 64;
  const int sr = tid >> 2, sc = (tid & 3) * 16;

  f32x4 acc[2][2];
#pragma unroll
  for (int i = 0; i < 2; ++i)
#pragma unroll
    for (int j = 0; j < 2; ++j) acc[i][j] = (f32x4){0.f, 0.f, 0.f, 0.f};

#pragma unroll 1
  for (int k0 = 0; k0 < D_; k0 += 64) {
    const uint4* src = (const uint4*)&X[(size_t)(m0 + sr) * D_ + k0 + sc];
    uint4 a0 = src[0], a1 = src[1];
    const float4* wsrc = (const float4*)&W[(size_t)(n0 + sr) * D_ + k0 + sc];
    float4 w0 = wsrc[0], w1 = wsrc[1], w2 = wsrc[2], w3 = wsrc[3];
    uint4 b0 = pack8(w0, w1), b1 = pack8(w2, w3);

    __syncthreads();
    {
      const int aw = (sr << 7) + (tid & 3) * 32;
      const int bw = ((64 + sr) << 7) + (tid & 3) * 32;
      *(uint4*)(shb + SWZ(aw)) = a0; *(uint4*)(shb + SWZ(aw + 16)) = a1;
      *(uint4*)(shb + SWZ(bw)) = b0; *(uint4*)(shb + SWZ(bw + 16)) = b1;
    }
    __syncthreads();

#pragma unroll
    for (int kw = 0; kw < 2; ++kw) {
      const int ar0 = ((wm * 32 + l15) << 7) + kw * 64 + lg * 16;
      const int ar1 = ((wm * 32 + 16 + l15) << 7) + kw * 64 + lg * 16;
      const int br0 = ((64 + wn * 32 + l15) << 7) + kw * 64 + lg * 16;
      const int br1 = ((64 + wn * 32 + 16 + l15) << 7) + kw * 64 + lg * 16;
      s16x8 af0 = *(const s16x8*)(shb + SWZ(ar0));
      s16x8 af1 = *(const s16x8*)(shb + SWZ(ar1));
      s16x8 bf0 = *(const s16x8*)(shb + SWZ(br0));
      s16x8 bf1 = *(const s16x8*)(shb + SWZ(br1));
      acc[0][0] = __builtin_amdgcn_mfma_f32_16x16x32_bf16(af0, bf0, acc[0][0], 0, 0, 0);
      acc[0][1] = __builtin_amdgcn_mfma_f32_16x16x32_bf16(af0, bf1, acc[0][1], 0, 0, 0);
      acc[1][0] = __builtin_amdgcn_mfma_f32_16x16x32_bf16(af1, bf0, acc[1][0], 0, 0, 0);
      acc[1][1] = __builtin_amdgcn_mfma_f32_16x16x32_bf16(af1, bf1, acc[1][1], 0, 0, 0);
    }
  }

  float bias_v[2];
  bias_v[0] = bias[n0 + wn * 32 + l15];
  bias_v[1] = bias[n0 + wn * 32 + 16 + l15];
#pragma unroll
  for (int am = 0; am < 2; ++am)
#pragma unroll
    for (int bn = 0; bn < 2; ++bn)
#pragma unroll
      for (int j = 0; j < 4; ++j) {
        const int row = m0 + wm * 32 + am * 16 + lg * 4 + j;
        const int col = n0 + wn * 32 + bn * 16 + l15;
        Y[(size_t)row * D_ + col] = acc[am][bn][j] + bias_v[bn];
      }
}

// ---------------------------------------------------------------------------
// Flash attention, swapped-operand MFMA, in-register softmax, packed mask.
// K/V double-buffered (early global issue, LDS write after compute, 1
// barrier/iter); all LDS XOR-swizzled; cvt_pk bf16 packs.
// R6 fix: V staging column offset sc folded into vbase (was dropped in R5).
// ---------------------------------------------------------------------------
constexpr float SCL = 0.18033688f;   // (1/sqrt(64)) * log2(e); log2-domain softmax

__global__ __launch_bounds__(256) void attn_mfma(
    const u16* __restrict__ qp, const u16* __restrict__ kp,
    const u16* __restrict__ vt, const u64* __restrict__ mbits,
    u16* __restrict__ ob)
{
  const int b = blockIdx.z, h = blockIdx.y;
  const int q0 = blockIdx.x * 64;
  const int tid = threadIdx.x;
  const int lane = tid & 63;
  const int w = tid >> 6;
  const int l15 = lane & 15, lg = lane >> 4;

  __shared__ __align__(128) u16 KV[2][2][64][64];  // [buf][K/V][row][col] 32KB
  __shared__ __align__(128) u16 Pl[4][16][64];     // per-wave P [q][key] 8KB
  char* kvb = (char*)KV;
  char* plb = (char*)Pl;

  const int qr = q0 + w * 16;

  // Q fragments (B-operand: rows = q = l15), held for the whole kernel
  const u16* qrow = qp + ((size_t)b * S_ + qr + l15) * D_ + h * HD_;
  const s16x8 qf0 = *(const s16x8*)(qrow + lg * 8);
  const s16x8 qf1 = *(const s16x8*)(qrow + 32 + lg * 8);

  f32x4 out[4];
#pragma unroll
  for (int dt = 0; dt < 4; ++dt) out[dt] = (f32x4){0.f, 0.f, 0.f, 0.f};
  float m_s = -3.0e38f, l_s = 0.f;   // per-lane stats for q-row l15 (log2 dom.)

  const int sr = tid >> 2;
  const int sc = (tid & 3) * 16;
  const u16* kbase = kp + (size_t)b * S_ * D_ + h * HD_;
  // R6 FIX: include the key-column offset sc here (R5 dropped it at the loads)
  const u16* vbase = vt + (((size_t)b * H_ + h) * 64 + sr) * (size_t)S_ + sc;
  const u64* mrow = mbits + ((size_t)b * S_ + qr + l15) * NT_;

  const int pbase = w * 2048 + l15 * 128;

  // ---- prologue: tile 0 ----
  uint4 rk0, rk1, rv0, rv1;
  {
    const u16* ksrc = kbase + (size_t)sr * D_ + sc;
    rk0 = *(const uint4*)ksrc; rk1 = *(const uint4*)(ksrc + 8);
    rv0 = *(const uint4*)vbase; rv1 = *(const uint4*)(vbase + 8);
    const int kb = (sr << 7) + (tid & 3) * 32;              // buf0, K
    const int vb = ((64 + sr) << 7) + (tid & 3) * 32;       // buf0, V
    *(uint4*)(kvb + SWZ(kb)) = rk0; *(uint4*)(kvb + SWZ(kb + 16)) = rk1;
    *(uint4*)(kvb + SWZ(vb)) = rv0; *(uint4*)(kvb + SWZ(vb + 16)) = rv1;
  }
  u64 msk = mrow[0];
  __syncthreads();

#pragma unroll 1
  for (int t = 0; t < NT_; ++t) {
    const int cur = t & 1;
    const bool more = (t + 1 < NT_);
    u64 msk_n = 0;
    if (more) {   // early issue of next tile's global loads
      const int kt = (t + 1) * 64;
      const u16* ksrc = kbase + (size_t)(kt + sr) * D_ + sc;
      rk0 = *(const uint4*)ksrc; rk1 = *(const uint4*)(ksrc + 8);
      rv0 = *(const uint4*)(vbase + kt); rv1 = *(const uint4*)(vbase + kt + 8);
      msk_n = mrow[t + 1];
    }

    const u64 sh = msk >> (lg * 4);    // bit (t4*16+r) = key t4*16+lg*4+r
    const int kbufbase = (cur * 2 + 0) * 64 * 128;
    const int vbufbase = (cur * 2 + 1) * 64 * 128;

    // ---- QK^T (swapped): z[t4][r] = S[t4*16+lg*4+r][l15] ----
    f32x4 z[4];
    __builtin_amdgcn_s_setprio(1);
#pragma unroll
    for (int t4 = 0; t4 < 4; ++t4) {
      const int kb = kbufbase + ((t4 * 16 + l15) << 7) + lg * 16;
      s16x8 kb0 = *(const s16x8*)(kvb + SWZ(kb));
      s16x8 kb1 = *(const s16x8*)(kvb + SWZ(kb + 64));
      f32x4 zz = (f32x4){0.f, 0.f, 0.f, 0.f};
      zz = __builtin_amdgcn_mfma_f32_16x16x32_bf16(kb0, qf0, zz, 0, 0, 0);
      zz = __builtin_amdgcn_mfma_f32_16x16x32_bf16(kb1, qf1, zz, 0, 0, 0);
      z[t4] = zz;
    }
    __builtin_amdgcn_s_setprio(0);

    // ---- masked scale (log2 domain), in-lane + 2-shfl row max ----
    float x[4][4];
#pragma unroll
    for (int t4 = 0; t4 < 4; ++t4) {
      unsigned int g = (unsigned int)(sh >> (t4 * 16)) & 0xFu;
#pragma unroll
      for (int r = 0; r < 4; ++r)
        x[t4][r] = ((g >> r) & 1u) ? z[t4][r] * SCL : -1.0e9f;
    }
    float mx = x[0][0];
#pragma unroll
    for (int t4 = 0; t4 < 4; ++t4)
#pragma unroll
      for (int r = 0; r < 4; ++r) mx = fmaxf(mx, x[t4][r]);
    mx = fmaxf(mx, __shfl_xor(mx, 16, 64));
    mx = fmaxf(mx, __shfl_xor(mx, 32, 64));
    const float mnew = fmaxf(m_s, mx);
    const float corr = exp2f(m_s - mnew);
    m_s = mnew;

    float ps = 0.f;
#pragma unroll
    for (int t4 = 0; t4 < 4; ++t4)
#pragma unroll
      for (int r = 0; r < 4; ++r) {
        float p = exp2f(x[t4][r] - mnew);
        x[t4][r] = p;
        ps += p;
      }
    ps += __shfl_xor(ps, 16, 64);
    ps += __shfl_xor(ps, 32, 64);
    l_s = l_s * corr + ps;

    // ---- P -> per-wave swizzled LDS (bf16) ----
#pragma unroll
    for (int t4 = 0; t4 < 4; ++t4) {
      uint2 pk;
      pk.x = cvt_pk2(x[t4][0], x[t4][1]);
      pk.y = cvt_pk2(x[t4][2], x[t4][3]);
      *(uint2*)(plb + SWZ(pbase + t4 * 32 + lg * 8)) = pk;
    }

    // rescale accumulators (lane-local corr)
#pragma unroll
    for (int dt = 0; dt < 4; ++dt)
#pragma unroll
      for (int r = 0; r < 4; ++r) out[dt][r] *= corr;

    // ---- PV (swapped): A = V^T rows (d), B = P rows (q = l15) ----
    s16x8 pa0 = *(const s16x8*)(plb + SWZ(pbase + lg * 16));
    s16x8 pa1 = *(const s16x8*)(plb + SWZ(pbase + 64 + lg * 16));
    __builtin_amdgcn_s_setprio(1);
#pragma unroll
    for (int dt = 0; dt < 4; ++dt) {
      const int vb = vbufbase + ((dt * 16 + l15) << 7) + lg * 16;
      s16x8 va0 = *(const s16x8*)(kvb + SWZ(vb));
      s16x8 va1 = *(const s16x8*)(kvb + SWZ(vb + 64));
      out[dt] = __builtin_amdgcn_mfma_f32_16x16x32_bf16(va0, pa0, out[dt], 0, 0, 0);
      out[dt] = __builtin_amdgcn_mfma_f32_16x16x32_bf16(va1, pa1, out[dt], 0, 0, 0);
    }
    __builtin_amdgcn_s_setprio(0);

    // ---- write next tile into the other buffer (vmcnt wait lands here) ----
    if (more) {
      const int nb = cur ^ 1;
      const int kb2 = (((nb * 2 + 0) * 64 + sr) << 7) + (tid & 3) * 32;
      const int vb2 = (((nb * 2 + 1) * 64 + sr) << 7) + (tid & 3) * 32;
      *(uint4*)(kvb + SWZ(kb2)) = rk0; *(uint4*)(kvb + SWZ(kb2 + 16)) = rk1;
      *(uint4*)(kvb + SWZ(vb2)) = rv0; *(uint4*)(kvb + SWZ(vb2 + 16)) = rv1;
      msk = msk_n;
    }
    __syncthreads();
  }

  // epilogue: q = l15, d = dt*16 + lg*4 + r -> bf16
  const float inv = 1.0f / l_s;
  u16* obase = ob + ((size_t)b * S_ + qr + l15) * D_ + h * HD_;
#pragma unroll
  for (int dt = 0; dt < 4; ++dt) {
    uint2 o;
    o.x = cvt_pk2(out[dt][0] * inv, out[dt][1] * inv);
    o.y = cvt_pk2(out[dt][2] * inv, out[dt][3] * inv);
    *(uint2*)&obase[dt * 16 + lg * 4] = o;
  }
}

// ---------------------------------------------------------------------------
extern "C" void kernel_launch(void* const* d_in, const int* in_sizes, int n_in,
                              void* d_out, int out_size, void* d_ws,
                              size_t ws_size, hipStream_t stream)
{
  const float* q_in = (const float*)d_in[0];
  const float* k_in = (const float*)d_in[1];
  const float* v_in = (const float*)d_in[2];
  const int*   mask = (const int*)d_in[3];
  const float* W1 = (const float*)d_in[4];
  const float* b1 = (const float*)d_in[5];
  const float* W2 = (const float*)d_in[6];
  const float* b2 = (const float*)d_in[7];
  const float* W3 = (const float*)d_in[8];
  const float* b3 = (const float*)d_in[9];
  const float* Wo = (const float*)d_in[10];
  const float* bo = (const float*)d_in[11];
  float* out = (float*)d_out;

  // workspace: qp, kp [M][D] bf16; vt [B*H*64][S] bf16; ob [M][D] bf16; mbits
  u16* qp = (u16*)d_ws;
  u16* kp = qp + (size_t)M_ * D_;
  u16* vtp = kp + (size_t)M_ * D_;
  u16* ob = vtp + (size_t)M_ * D_;
  u64* mbits = (u64*)(ob + (size_t)M_ * D_);

  dim3 blk(256);
  mask_pack<<<512, blk, 0, stream>>>(mask, mbits);
  gemm_qkv<<<dim3(M_ / 64, D_ / 64, 3), blk, 0, stream>>>(
      q_in, W1, b1, qp, k_in, W2, b2, kp, v_in, W3, b3, vtp);
  attn_mfma<<<dim3(S_ / 64, H_, B_), blk, 0, stream>>>(qp, kp, vtp, mbits, ob);
  gemm_oproj<<<dim3(M_ / 64, D_ / 64), blk, 0, stream>>>(ob, Wo, bo, out);
}

// Round 7
// 118.408 us; speedup vs baseline: 13.1015x; 1.0268x over previous
//
#include <hip/hip_runtime.h>
#include <hip/hip_bf16.h>
#include <math.h>

// MultiHeadAttention: B=2, S=2048, D=512, H=8, HD=64
constexpr int B_ = 2, S_ = 2048, D_ = 512, H_ = 8, HD_ = 64;
constexpr int M_ = B_ * S_;
constexpr int NT_ = S_ / 64;          // 32 key tiles / mask u64 slots per row
constexpr int NSPLIT = 2;             // split-K factor for attention
constexpr int NT2 = NT_ / NSPLIT;     // 16 tiles per block
constexpr int ROWS = B_ * S_ * H_;    // 32768 (q-row, head) pairs

typedef short s16x8 __attribute__((ext_vector_type(8)));    // 8 bf16 (A/B frag)
typedef float f32x4 __attribute__((ext_vector_type(4)));    // C/D frag
typedef unsigned short u16;
typedef unsigned long long u64;

// XOR swizzle for 128B-row LDS tiles: flips byte bits 4-6 by row&7.
#define SWZ(b) ((b) ^ ((((b) >> 7) & 7) << 4))

static __device__ __forceinline__ unsigned int cvt_pk2(float lo, float hi) {
  __hip_bfloat162 h = __float22bfloat162_rn(make_float2(lo, hi));
  return *(unsigned int*)&h;
}
static __device__ __forceinline__ u16 cvt1(float f) {
  __hip_bfloat16 h = __float2bfloat16(f);
  return *(u16*)&h;
}
static __device__ __forceinline__ uint4 pack8(float4 a, float4 b) {
  uint4 r;
  r.x = cvt_pk2(a.x, a.y); r.y = cvt_pk2(a.z, a.w);
  r.z = cvt_pk2(b.x, b.y); r.w = cvt_pk2(b.z, b.w);
  return r;
}

// ---------------------------------------------------------------------------
// Mask int32 -> packed bits: mbits[b*S + q][tile] = ballot of 64 keys.
// ---------------------------------------------------------------------------
__global__ __launch_bounds__(256) void mask_pack(
    const int* __restrict__ mask, u64* __restrict__ mbits)
{
  const int lane = threadIdx.x & 63;
  const int wid = (blockIdx.x * blockDim.x + threadIdx.x) >> 6;
  const int nw = (gridDim.x * blockDim.x) >> 6;
  const int nslots = B_ * S_ * NT_;
  for (int s = wid; s < nslots; s += nw) {
    int v = mask[(size_t)s * 64 + lane];
    u64 bits = __ballot(v != 0);
    if (lane == 0) mbits[s] = bits;
  }
}

// ---------------------------------------------------------------------------
// Fused QKV projection (unchanged from R6).
// ---------------------------------------------------------------------------
__global__ __launch_bounds__(256) void gemm_qkv(
    const float* __restrict__ Xq, const float* __restrict__ Wq,
    const float* __restrict__ bq, u16* __restrict__ Yq,
    const float* __restrict__ Xk, const float* __restrict__ Wk,
    const float* __restrict__ bk, u16* __restrict__ Yk,
    const float* __restrict__ Xv, const float* __restrict__ Wv,
    const float* __restrict__ bv, u16* __restrict__ Yv)
{
  const float* X; const float* W; const float* bias; u16* Y;
  const int z = blockIdx.z;
  if (z == 0)      { X = Xq; W = Wq; bias = bq; Y = Yq; }
  else if (z == 1) { X = Xk; W = Wk; bias = bk; Y = Yk; }
  else             { X = Xv; W = Wv; bias = bv; Y = Yv; }

  __shared__ __align__(128) u16 SH[2][64][64];
  char* shb = (char*)SH;

  const int tid = threadIdx.x;
  const int lane = tid & 63, w = tid >> 6;
  const int l15 = lane & 15, lg = lane >> 4;
  const int wm = w >> 1, wn = w & 1;
  const int m0 = blockIdx.x * 64, n0 = blockIdx.y * 64;
  const int sr = tid >> 2, sc = (tid & 3) * 16;

  f32x4 acc[2][2];
#pragma unroll
  for (int i = 0; i < 2; ++i)
#pragma unroll
    for (int j = 0; j < 2; ++j) acc[i][j] = (f32x4){0.f, 0.f, 0.f, 0.f};

#pragma unroll 1
  for (int k0 = 0; k0 < D_; k0 += 64) {
    const float4* src = (const float4*)&X[(size_t)(m0 + sr) * D_ + k0 + sc];
    float4 f0 = src[0], f1 = src[1], f2 = src[2], f3 = src[3];
    uint4 a0 = pack8(f0, f1), a1 = pack8(f2, f3);
    const float4* wsrc = (const float4*)&W[(size_t)(n0 + sr) * D_ + k0 + sc];
    float4 w0 = wsrc[0], w1 = wsrc[1], w2 = wsrc[2], w3 = wsrc[3];
    uint4 b0 = pack8(w0, w1), b1 = pack8(w2, w3);

    __syncthreads();
    {
      const int aw = (sr << 7) + (tid & 3) * 32;
      const int bw = ((64 + sr) << 7) + (tid & 3) * 32;
      *(uint4*)(shb + SWZ(aw)) = a0; *(uint4*)(shb + SWZ(aw + 16)) = a1;
      *(uint4*)(shb + SWZ(bw)) = b0; *(uint4*)(shb + SWZ(bw + 16)) = b1;
    }
    __syncthreads();

#pragma unroll
    for (int kw = 0; kw < 2; ++kw) {
      const int ar0 = ((wm * 32 + l15) << 7) + kw * 64 + lg * 16;
      const int ar1 = ((wm * 32 + 16 + l15) << 7) + kw * 64 + lg * 16;
      const int br0 = ((64 + wn * 32 + l15) << 7) + kw * 64 + lg * 16;
      const int br1 = ((64 + wn * 32 + 16 + l15) << 7) + kw * 64 + lg * 16;
      s16x8 af0 = *(const s16x8*)(shb + SWZ(ar0));
      s16x8 af1 = *(const s16x8*)(shb + SWZ(ar1));
      s16x8 bf0 = *(const s16x8*)(shb + SWZ(br0));
      s16x8 bf1 = *(const s16x8*)(shb + SWZ(br1));
      acc[0][0] = __builtin_amdgcn_mfma_f32_16x16x32_bf16(af0, bf0, acc[0][0], 0, 0, 0);
      acc[0][1] = __builtin_amdgcn_mfma_f32_16x16x32_bf16(af0, bf1, acc[0][1], 0, 0, 0);
      acc[1][0] = __builtin_amdgcn_mfma_f32_16x16x32_bf16(af1, bf0, acc[1][0], 0, 0, 0);
      acc[1][1] = __builtin_amdgcn_mfma_f32_16x16x32_bf16(af1, bf1, acc[1][1], 0, 0, 0);
    }
  }

  float bias_v[2];
  bias_v[0] = bias[n0 + wn * 32 + l15];
  bias_v[1] = bias[n0 + wn * 32 + 16 + l15];

  if (z != 2) {
#pragma unroll
    for (int am = 0; am < 2; ++am)
#pragma unroll
      for (int bn = 0; bn < 2; ++bn)
#pragma unroll
        for (int j = 0; j < 4; ++j) {
          const int row = m0 + wm * 32 + am * 16 + lg * 4 + j;
          const int col = n0 + wn * 32 + bn * 16 + l15;
          Y[(size_t)row * D_ + col] = cvt1(acc[am][bn][j] + bias_v[bn]);
        }
  } else {
    __syncthreads();
#pragma unroll
    for (int am = 0; am < 2; ++am)
#pragma unroll
      for (int bn = 0; bn < 2; ++bn) {
        const int dd = wn * 32 + bn * 16 + l15;
        const int sl = wm * 32 + am * 16 + lg * 4;
        ushort4 pk;
        pk.x = cvt1(acc[am][bn][0] + bias_v[bn]);
        pk.y = cvt1(acc[am][bn][1] + bias_v[bn]);
        pk.z = cvt1(acc[am][bn][2] + bias_v[bn]);
        pk.w = cvt1(acc[am][bn][3] + bias_v[bn]);
        const int cw = (dd << 7) + sl * 2;
        *(ushort4*)(shb + SWZ(cw)) = pk;
      }
    __syncthreads();
    const int batch = m0 >> 11, sb = m0 & (S_ - 1);
    const int cr = (sr << 7) + (tid & 3) * 32;
    uint4 c0 = *(uint4*)(shb + SWZ(cr));
    uint4 c1 = *(uint4*)(shb + SWZ(cr + 16));
    u16* dst = &Y[(((size_t)batch * H_ + blockIdx.y) * 64 + sr) * S_ + sb + sc];
    *(uint4*)dst = c0;
    *(uint4*)(dst + 8) = c1;
  }
}

// ---------------------------------------------------------------------------
// Out projection (unchanged from R6).
// ---------------------------------------------------------------------------
__global__ __launch_bounds__(256) void gemm_oproj(
    const u16* __restrict__ X, const float* __restrict__ W,
    const float* __restrict__ bias, float* __restrict__ Y)
{
  __shared__ __align__(128) u16 SH[2][64][64];
  char* shb = (char*)SH;

  const int tid = threadIdx.x;
  const int lane = tid & 63, w = tid >> 6;
  const int l15 = lane & 15, lg = lane >> 4;
  const int wm = w >> 1, wn = w & 1;
  const int m0 = blockIdx.x * 64, n0 = blockIdx.y * 64;
  const int sr = tid >> 2, sc = (tid & 3) * 16;

  f32x4 acc[2][2];
#pragma unroll
  for (int i = 0; i < 2; ++i)
#pragma unroll
    for (int j = 0; j < 2; ++j) acc[i][j] = (f32x4){0.f, 0.f, 0.f, 0.f};

#pragma unroll 1
  for (int k0 = 0; k0 < D_; k0 += 64) {
    const uint4* src = (const uint4*)&X[(size_t)(m0 + sr) * D_ + k0 + sc];
    uint4 a0 = src[0], a1 = src[1];
    const float4* wsrc = (const float4*)&W[(size_t)(n0 + sr) * D_ + k0 + sc];
    float4 w0 = wsrc[0], w1 = wsrc[1], w2 = wsrc[2], w3 = wsrc[3];
    uint4 b0 = pack8(w0, w1), b1 = pack8(w2, w3);

    __syncthreads();
    {
      const int aw = (sr << 7) + (tid & 3) * 32;
      const int bw = ((64 + sr) << 7) + (tid & 3) * 32;
      *(uint4*)(shb + SWZ(aw)) = a0; *(uint4*)(shb + SWZ(aw + 16)) = a1;
      *(uint4*)(shb + SWZ(bw)) = b0; *(uint4*)(shb + SWZ(bw + 16)) = b1;
    }
    __syncthreads();

#pragma unroll
    for (int kw = 0; kw < 2; ++kw) {
      const int ar0 = ((wm * 32 + l15) << 7) + kw * 64 + lg * 16;
      const int ar1 = ((wm * 32 + 16 + l15) << 7) + kw * 64 + lg * 16;
      const int br0 = ((64 + wn * 32 + l15) << 7) + kw * 64 + lg * 16;
      const int br1 = ((64 + wn * 32 + 16 + l15) << 7) + kw * 64 + lg * 16;
      s16x8 af0 = *(const s16x8*)(shb + SWZ(ar0));
      s16x8 af1 = *(const s16x8*)(shb + SWZ(ar1));
      s16x8 bf0 = *(const s16x8*)(shb + SWZ(br0));
      s16x8 bf1 = *(const s16x8*)(shb + SWZ(br1));
      acc[0][0] = __builtin_amdgcn_mfma_f32_16x16x32_bf16(af0, bf0, acc[0][0], 0, 0, 0);
      acc[0][1] = __builtin_amdgcn_mfma_f32_16x16x32_bf16(af0, bf1, acc[0][1], 0, 0, 0);
      acc[1][0] = __builtin_amdgcn_mfma_f32_16x16x32_bf16(af1, bf0, acc[1][0], 0, 0, 0);
      acc[1][1] = __builtin_amdgcn_mfma_f32_16x16x32_bf16(af1, bf1, acc[1][1], 0, 0, 0);
    }
  }

  float bias_v[2];
  bias_v[0] = bias[n0 + wn * 32 + l15];
  bias_v[1] = bias[n0 + wn * 32 + 16 + l15];
#pragma unroll
  for (int am = 0; am < 2; ++am)
#pragma unroll
    for (int bn = 0; bn < 2; ++bn)
#pragma unroll
      for (int j = 0; j < 4; ++j) {
        const int row = m0 + wm * 32 + am * 16 + lg * 4 + j;
        const int col = n0 + wn * 32 + bn * 16 + l15;
        Y[(size_t)row * D_ + col] = acc[am][bn][j] + bias_v[bn];
      }
}

// ---------------------------------------------------------------------------
// Split-K flash attention (half of S per block). Writes unnormalized fp32
// partials po[half][rowi][64] + stats pm/pl[half][rowi] (log2 domain).
// rowi = (b*S + q)*H + h. Otherwise identical to R6's verified structure.
// ---------------------------------------------------------------------------
constexpr float SCL = 0.18033688f;   // (1/sqrt(64)) * log2(e)

__global__ __launch_bounds__(256) void attn_mfma(
    const u16* __restrict__ qp, const u16* __restrict__ kp,
    const u16* __restrict__ vt, const u64* __restrict__ mbits,
    float* __restrict__ po, float* __restrict__ pm, float* __restrict__ pl)
{
  const int b = blockIdx.z >> 1, half = blockIdx.z & 1;
  const int h = blockIdx.y;
  const int q0 = blockIdx.x * 64;
  const int kt0 = half * (S_ / NSPLIT);        // 0 or 1024
  const int tid = threadIdx.x;
  const int lane = tid & 63;
  const int w = tid >> 6;
  const int l15 = lane & 15, lg = lane >> 4;

  __shared__ __align__(128) u16 KV[2][2][64][64];  // [buf][K/V][row][col] 32KB
  __shared__ __align__(128) u16 Pl[4][16][64];     // per-wave P [q][key] 8KB
  char* kvb = (char*)KV;
  char* plb = (char*)Pl;

  const int qr = q0 + w * 16;

  const u16* qrow = qp + ((size_t)b * S_ + qr + l15) * D_ + h * HD_;
  const s16x8 qf0 = *(const s16x8*)(qrow + lg * 8);
  const s16x8 qf1 = *(const s16x8*)(qrow + 32 + lg * 8);

  f32x4 out[4];
#pragma unroll
  for (int dt = 0; dt < 4; ++dt) out[dt] = (f32x4){0.f, 0.f, 0.f, 0.f};
  float m_s = -3.0e38f, l_s = 0.f;

  const int sr = tid >> 2;
  const int sc = (tid & 3) * 16;
  const u16* kbase = kp + (size_t)b * S_ * D_ + h * HD_;
  const u16* vbase = vt + (((size_t)b * H_ + h) * 64 + sr) * (size_t)S_ + kt0 + sc;
  const u64* mrow = mbits + ((size_t)b * S_ + qr + l15) * NT_ + half * NT2;

  const int pbase = w * 2048 + l15 * 128;

  // ---- prologue: tile 0 of this half ----
  uint4 rk0, rk1, rv0, rv1;
  {
    const u16* ksrc = kbase + (size_t)(kt0 + sr) * D_ + sc;
    rk0 = *(const uint4*)ksrc; rk1 = *(const uint4*)(ksrc + 8);
    rv0 = *(const uint4*)vbase; rv1 = *(const uint4*)(vbase + 8);
    const int kb = (sr << 7) + (tid & 3) * 32;
    const int vb = ((64 + sr) << 7) + (tid & 3) * 32;
    *(uint4*)(kvb + SWZ(kb)) = rk0; *(uint4*)(kvb + SWZ(kb + 16)) = rk1;
    *(uint4*)(kvb + SWZ(vb)) = rv0; *(uint4*)(kvb + SWZ(vb + 16)) = rv1;
  }
  u64 msk = mrow[0];
  __syncthreads();

#pragma unroll 1
  for (int t = 0; t < NT2; ++t) {
    const int cur = t & 1;
    const bool more = (t + 1 < NT2);
    u64 msk_n = 0;
    if (more) {
      const int kt = (t + 1) * 64;
      const u16* ksrc = kbase + (size_t)(kt0 + kt + sr) * D_ + sc;
      rk0 = *(const uint4*)ksrc; rk1 = *(const uint4*)(ksrc + 8);
      rv0 = *(const uint4*)(vbase + kt); rv1 = *(const uint4*)(vbase + kt + 8);
      msk_n = mrow[t + 1];
    }

    const u64 sh = msk >> (lg * 4);
    const int kbufbase = (cur * 2 + 0) * 64 * 128;
    const int vbufbase = (cur * 2 + 1) * 64 * 128;

    // ---- QK^T (swapped) ----
    f32x4 z[4];
    __builtin_amdgcn_s_setprio(1);
#pragma unroll
    for (int t4 = 0; t4 < 4; ++t4) {
      const int kb = kbufbase + ((t4 * 16 + l15) << 7) + lg * 16;
      s16x8 kb0 = *(const s16x8*)(kvb + SWZ(kb));
      s16x8 kb1 = *(const s16x8*)(kvb + SWZ(kb + 64));
      f32x4 zz = (f32x4){0.f, 0.f, 0.f, 0.f};
      zz = __builtin_amdgcn_mfma_f32_16x16x32_bf16(kb0, qf0, zz, 0, 0, 0);
      zz = __builtin_amdgcn_mfma_f32_16x16x32_bf16(kb1, qf1, zz, 0, 0, 0);
      z[t4] = zz;
    }
    __builtin_amdgcn_s_setprio(0);

    // ---- masked scale + online softmax ----
    float x[4][4];
#pragma unroll
    for (int t4 = 0; t4 < 4; ++t4) {
      unsigned int g = (unsigned int)(sh >> (t4 * 16)) & 0xFu;
#pragma unroll
      for (int r = 0; r < 4; ++r)
        x[t4][r] = ((g >> r) & 1u) ? z[t4][r] * SCL : -1.0e9f;
    }
    float mx = x[0][0];
#pragma unroll
    for (int t4 = 0; t4 < 4; ++t4)
#pragma unroll
      for (int r = 0; r < 4; ++r) mx = fmaxf(mx, x[t4][r]);
    mx = fmaxf(mx, __shfl_xor(mx, 16, 64));
    mx = fmaxf(mx, __shfl_xor(mx, 32, 64));
    const float mnew = fmaxf(m_s, mx);
    const float corr = exp2f(m_s - mnew);
    m_s = mnew;

    float ps = 0.f;
#pragma unroll
    for (int t4 = 0; t4 < 4; ++t4)
#pragma unroll
      for (int r = 0; r < 4; ++r) {
        float p = exp2f(x[t4][r] - mnew);
        x[t4][r] = p;
        ps += p;
      }
    ps += __shfl_xor(ps, 16, 64);
    ps += __shfl_xor(ps, 32, 64);
    l_s = l_s * corr + ps;

    // ---- P -> per-wave swizzled LDS ----
#pragma unroll
    for (int t4 = 0; t4 < 4; ++t4) {
      uint2 pk;
      pk.x = cvt_pk2(x[t4][0], x[t4][1]);
      pk.y = cvt_pk2(x[t4][2], x[t4][3]);
      *(uint2*)(plb + SWZ(pbase + t4 * 32 + lg * 8)) = pk;
    }

#pragma unroll
    for (int dt = 0; dt < 4; ++dt)
#pragma unroll
      for (int r = 0; r < 4; ++r) out[dt][r] *= corr;

    // ---- PV (swapped) ----
    s16x8 pa0 = *(const s16x8*)(plb + SWZ(pbase + lg * 16));
    s16x8 pa1 = *(const s16x8*)(plb + SWZ(pbase + 64 + lg * 16));
    __builtin_amdgcn_s_setprio(1);
#pragma unroll
    for (int dt = 0; dt < 4; ++dt) {
      const int vb = vbufbase + ((dt * 16 + l15) << 7) + lg * 16;
      s16x8 va0 = *(const s16x8*)(kvb + SWZ(vb));
      s16x8 va1 = *(const s16x8*)(kvb + SWZ(vb + 64));
      out[dt] = __builtin_amdgcn_mfma_f32_16x16x32_bf16(va0, pa0, out[dt], 0, 0, 0);
      out[dt] = __builtin_amdgcn_mfma_f32_16x16x32_bf16(va1, pa1, out[dt], 0, 0, 0);
    }
    __builtin_amdgcn_s_setprio(0);

    if (more) {
      const int nb = cur ^ 1;
      const int kb2 = (((nb * 2 + 0) * 64 + sr) << 7) + (tid & 3) * 32;
      const int vb2 = (((nb * 2 + 1) * 64 + sr) << 7) + (tid & 3) * 32;
      *(uint4*)(kvb + SWZ(kb2)) = rk0; *(uint4*)(kvb + SWZ(kb2 + 16)) = rk1;
      *(uint4*)(kvb + SWZ(vb2)) = rv0; *(uint4*)(kvb + SWZ(vb2 + 16)) = rv1;
      msk = msk_n;
    }
    __syncthreads();
  }

  // ---- epilogue: unnormalized fp32 partials ----
  const int rowi = ((b * S_ + qr + l15) * H_) + h;
  float* pobase = po + ((size_t)half * ROWS + rowi) * 64;
#pragma unroll
  for (int dt = 0; dt < 4; ++dt) {
    float4 o = make_float4(out[dt][0], out[dt][1], out[dt][2], out[dt][3]);
    *(float4*)&pobase[dt * 16 + lg * 4] = o;
  }
  if (lg == 0) {
    pm[(size_t)half * ROWS + rowi] = m_s;
    pl[(size_t)half * ROWS + rowi] = l_s;
  }
}

// ---------------------------------------------------------------------------
// Combine the NSPLIT partials -> bf16 ob[M][D].
// thread -> 4 consecutive d of one rowi. rowi = (b*S+q)*H + h.
// ---------------------------------------------------------------------------
__global__ __launch_bounds__(256) void attn_combine(
    const float* __restrict__ po, const float* __restrict__ pm,
    const float* __restrict__ pl, u16* __restrict__ ob)
{
  const int gid = blockIdx.x * 256 + threadIdx.x;   // 524288 threads
  const int row = gid >> 4;                         // rowi
  const int d0 = (gid & 15) * 4;

  float4 o1 = *(const float4*)&po[(size_t)row * 64 + d0];
  float4 o2 = *(const float4*)&po[(size_t)(ROWS + row) * 64 + d0];
  const float m1 = pm[row], m2 = pm[ROWS + row];
  const float l1 = pl[row], l2 = pl[ROWS + row];
  const float m = fmaxf(m1, m2);
  const float w1 = exp2f(m1 - m), w2 = exp2f(m2 - m);
  const float inv = 1.0f / (l1 * w1 + l2 * w2);

  const int bq = row >> 3, h = row & 7;
  uint2 o;
  o.x = cvt_pk2((o1.x * w1 + o2.x * w2) * inv, (o1.y * w1 + o2.y * w2) * inv);
  o.y = cvt_pk2((o1.z * w1 + o2.z * w2) * inv, (o1.w * w1 + o2.w * w2) * inv);
  *(uint2*)&ob[(size_t)bq * D_ + h * 64 + d0] = o;
}

// ---------------------------------------------------------------------------
extern "C" void kernel_launch(void* const* d_in, const int* in_sizes, int n_in,
                              void* d_out, int out_size, void* d_ws,
                              size_t ws_size, hipStream_t stream)
{
  const float* q_in = (const float*)d_in[0];
  const float* k_in = (const float*)d_in[1];
  const float* v_in = (const float*)d_in[2];
  const int*   mask = (const int*)d_in[3];
  const float* W1 = (const float*)d_in[4];
  const float* b1 = (const float*)d_in[5];
  const float* W2 = (const float*)d_in[6];
  const float* b2 = (const float*)d_in[7];
  const float* W3 = (const float*)d_in[8];
  const float* b3 = (const float*)d_in[9];
  const float* Wo = (const float*)d_in[10];
  const float* bo = (const float*)d_in[11];
  float* out = (float*)d_out;

  // workspace layout (29.5MB):
  //   [0,4M)    qp bf16            (reused as ob by combine/oproj)
  //   [4,8M)    kp bf16
  //   [8,12M)   vt bf16
  //   [12,13M)  mbits
  //   [13,13.25M) pm fp32 [2][ROWS]
  //   [13.25,13.5M) pl fp32
  //   [13.5,29.5M) po fp32 [2][ROWS][64]
  char* ws = (char*)d_ws;
  u16* qp = (u16*)ws;
  u16* kp = (u16*)(ws + (4u << 20));
  u16* vtp = (u16*)(ws + (8u << 20));
  u64* mbits = (u64*)(ws + (12u << 20));
  float* pm = (float*)(ws + (13u << 20));
  float* pl = (float*)(ws + (13u << 20) + (ROWS * NSPLIT * 4));
  float* po = (float*)(ws + (13u << 20) + (512u << 10));
  u16* ob = qp;   // qp dead after attn_mfma

  dim3 blk(256);
  mask_pack<<<512, blk, 0, stream>>>(mask, mbits);
  gemm_qkv<<<dim3(M_ / 64, D_ / 64, 3), blk, 0, stream>>>(
      q_in, W1, b1, qp, k_in, W2, b2, kp, v_in, W3, b3, vtp);
  attn_mfma<<<dim3(S_ / 64, H_, B_ * NSPLIT), blk, 0, stream>>>(
      qp, kp, vtp, mbits, po, pm, pl);
  attn_combine<<<ROWS * 16 / 256, blk, 0, stream>>>(po, pm, pl, ob);
  gemm_oproj<<<dim3(M_ / 64, D_ / 64), blk, 0, stream>>>(ob, Wo, bo, out);
}